// Round 3
// baseline (2023.705 us; speedup 1.0000x reference)
//
#include <hip/hip_runtime.h>
#include <math.h>

#define N_NODES 100000
#define N_EDGES 3200000
#define IN_DIM  128
#define OUT_DIM 64

#define BSHIFT   7
#define BNODES   128                                   // nodes per bucket
#define NBUCKETS ((N_NODES + BNODES - 1) / BNODES)     // 782
#define NBINBLK  256
#define CHUNK    (N_EDGES / NBINBLK)                   // 12500 (exact)

// ---------------------------------------------------------------------------
// Kernel 1: base = feature @ W_lin ; u1 = tanh(base)
// ---------------------------------------------------------------------------
__global__ __launch_bounds__(256) void gemm_base_tanh(
    const float* __restrict__ feature,
    const float* __restrict__ Wlin,
    float* __restrict__ base,
    float* __restrict__ u1)
{
    int row = blockIdx.x * 256 + threadIdx.x;
    if (row >= N_NODES) return;

    const float4* frow = reinterpret_cast<const float4*>(feature + (size_t)row * IN_DIM);
    const float4* Wv   = reinterpret_cast<const float4*>(Wlin);   // [IN_DIM][16] float4

    float4 acc[16];
#pragma unroll
    for (int j = 0; j < 16; ++j) acc[j] = make_float4(0.f, 0.f, 0.f, 0.f);

    for (int k4 = 0; k4 < IN_DIM / 4; ++k4) {
        float4 f = frow[k4];
#pragma unroll
        for (int kk = 0; kk < 4; ++kk) {
            float fk = (kk == 0) ? f.x : (kk == 1) ? f.y : (kk == 2) ? f.z : f.w;
            const float4* wr = Wv + (size_t)(k4 * 4 + kk) * (OUT_DIM / 4);
#pragma unroll
            for (int j = 0; j < 16; ++j) {
                float4 w = wr[j];
                acc[j].x = fmaf(fk, w.x, acc[j].x);
                acc[j].y = fmaf(fk, w.y, acc[j].y);
                acc[j].z = fmaf(fk, w.z, acc[j].z);
                acc[j].w = fmaf(fk, w.w, acc[j].w);
            }
        }
    }

    float4* brow = reinterpret_cast<float4*>(base + (size_t)row * OUT_DIM);
    float4* urow = reinterpret_cast<float4*>(u1   + (size_t)row * OUT_DIM);
#pragma unroll
    for (int j = 0; j < 16; ++j) {
        brow[j] = acc[j];
        float4 t;
        t.x = tanhf(acc[j].x);
        t.y = tanhf(acc[j].y);
        t.z = tanhf(acc[j].z);
        t.w = tanhf(acc[j].w);
        urow[j] = t;
    }
}

// ---------------------------------------------------------------------------
// Binning phase: bucket edges by dst>>7.  All contention stays in LDS.
// H layout is bucket-major: H[k*NBINBLK + b] so the scan is linear.
// ---------------------------------------------------------------------------
__global__ __launch_bounds__(256) void bin_hist(
    const int* __restrict__ dst, int* __restrict__ H)
{
    __shared__ int h[NBUCKETS];
    for (int k = threadIdx.x; k < NBUCKETS; k += 256) h[k] = 0;
    __syncthreads();

    int b = blockIdx.x;
    int beg = b * CHUNK, end = beg + CHUNK;
    for (int i = beg + threadIdx.x; i < end; i += 256)
        atomicAdd(&h[dst[i] >> BSHIFT], 1);
    __syncthreads();

    for (int k = threadIdx.x; k < NBUCKETS; k += 256)
        H[k * NBINBLK + b] = h[k];
}

__global__ __launch_bounds__(1024) void bin_scan(int* __restrict__ H)
{
    __shared__ int sums[1024];
    const int T = NBUCKETS * NBINBLK;          // 200192
    const int C = (T + 1023) / 1024;           // 196
    int t = threadIdx.x;
    int beg = t * C;
    int end = beg + C; if (end > T) end = T;
    if (beg > T) beg = T;

    int s = 0;
    for (int i = beg; i < end; ++i) s += H[i];
    sums[t] = s;
    __syncthreads();

    for (int off = 1; off < 1024; off <<= 1) {
        int v = (t >= off) ? sums[t - off] : 0;
        __syncthreads();
        sums[t] += v;
        __syncthreads();
    }

    int excl = (t == 0) ? 0 : sums[t - 1];
    for (int i = beg; i < end; ++i) { int v = H[i]; H[i] = excl; excl += v; }
    if (t == 1023) H[T] = sums[1023];          // == N_EDGES
}

__global__ __launch_bounds__(256) void bin_scatter(
    const int* __restrict__ src,
    const int* __restrict__ dst,
    const int* __restrict__ H,
    int* __restrict__ ebuf)
{
    __shared__ int cur[NBUCKETS];
    int b = blockIdx.x;
    for (int k = threadIdx.x; k < NBUCKETS; k += 256)
        cur[k] = H[k * NBINBLK + b];
    __syncthreads();

    int beg = b * CHUNK, end = beg + CHUNK;
    for (int i = beg + threadIdx.x; i < end; i += 256) {
        int d = dst[i];
        int k = d >> BSHIFT;
        int p = atomicAdd(&cur[k], 1);
        // pack: src (17 bits) | dlocal (7 bits) << 17
        ebuf[p] = src[i] | ((d & (BNODES - 1)) << 17);
    }
}

// ---------------------------------------------------------------------------
// Gather: one block per bucket, 128x64 f32 tile in LDS (32 KB, 5 blocks/CU).
// Wave = edge, lane = column. LDS atomics only; m written coalesced once.
// ---------------------------------------------------------------------------
__global__ __launch_bounds__(256) void bucket_gather(
    const int* __restrict__ H,
    const int* __restrict__ ebuf,
    const float* __restrict__ u1,
    float* __restrict__ m)
{
    __shared__ float tile[BNODES * OUT_DIM];   // 32 KB
    int k = blockIdx.x;

    for (int i = threadIdx.x; i < BNODES * OUT_DIM; i += 256) tile[i] = 0.f;
    __syncthreads();

    int beg = H[(size_t)k * NBINBLK];
    int end = H[(size_t)(k + 1) * NBINBLK];

    int lane = threadIdx.x & 63;
    int wv   = threadIdx.x >> 6;               // 0..3
    int cnt  = end - beg;
    int nfull = cnt & ~15;                     // 16 edges per block-iteration

    for (int e0 = beg + wv * 4; e0 < beg + nfull; e0 += 16) {
        int a = ebuf[e0];
        int b2 = ebuf[e0 + 1];
        int c = ebuf[e0 + 2];
        int d = ebuf[e0 + 3];
        float v0 = u1[(size_t)(a  & 0x1FFFF) * OUT_DIM + lane];
        float v1 = u1[(size_t)(b2 & 0x1FFFF) * OUT_DIM + lane];
        float v2 = u1[(size_t)(c  & 0x1FFFF) * OUT_DIM + lane];
        float v3 = u1[(size_t)(d  & 0x1FFFF) * OUT_DIM + lane];
        atomicAdd(&tile[(a  >> 17) * OUT_DIM + lane], v0);
        atomicAdd(&tile[(b2 >> 17) * OUT_DIM + lane], v1);
        atomicAdd(&tile[(c  >> 17) * OUT_DIM + lane], v2);
        atomicAdd(&tile[(d  >> 17) * OUT_DIM + lane], v3);
    }
    for (int e = beg + nfull + wv; e < end; e += 4) {
        int en = ebuf[e];
        atomicAdd(&tile[(en >> 17) * OUT_DIM + lane],
                  u1[(size_t)(en & 0x1FFFF) * OUT_DIM + lane]);
    }
    __syncthreads();

    int node0 = k * BNODES;
    int rows  = N_NODES - node0; if (rows > BNODES) rows = BNODES;
    float4* mg = reinterpret_cast<float4*>(m + (size_t)node0 * OUT_DIM);
    const float4* tl = reinterpret_cast<const float4*>(tile);
    int nf4 = rows * (OUT_DIM / 4);
    for (int i = threadIdx.x; i < nf4; i += 256) mg[i] = tl[i];
}

// ---------------------------------------------------------------------------
// Kernel 3: out = tanh(base + relu(m @ W_d1) @ W_d2)
// ---------------------------------------------------------------------------
__global__ __launch_bounds__(256) void dense_tanh(
    const float* __restrict__ m,
    const float* __restrict__ W1,
    const float* __restrict__ W2,
    const float* __restrict__ base,
    float* __restrict__ out)
{
    int row = blockIdx.x * 256 + threadIdx.x;
    if (row >= N_NODES) return;

    const float4* mrow = reinterpret_cast<const float4*>(m + (size_t)row * OUT_DIM);
    const float4* W1v  = reinterpret_cast<const float4*>(W1);  // [64][16] float4
    const float4* W2v  = reinterpret_cast<const float4*>(W2);

    float4 t[16];
#pragma unroll
    for (int j = 0; j < 16; ++j) t[j] = make_float4(0.f, 0.f, 0.f, 0.f);

    for (int k4 = 0; k4 < OUT_DIM / 4; ++k4) {
        float4 mv = mrow[k4];
#pragma unroll
        for (int kk = 0; kk < 4; ++kk) {
            float mk = (kk == 0) ? mv.x : (kk == 1) ? mv.y : (kk == 2) ? mv.z : mv.w;
            const float4* wr = W1v + (size_t)(k4 * 4 + kk) * 16;
#pragma unroll
            for (int j = 0; j < 16; ++j) {
                float4 w = wr[j];
                t[j].x = fmaf(mk, w.x, t[j].x);
                t[j].y = fmaf(mk, w.y, t[j].y);
                t[j].z = fmaf(mk, w.z, t[j].z);
                t[j].w = fmaf(mk, w.w, t[j].w);
            }
        }
    }
#pragma unroll
    for (int j = 0; j < 16; ++j) {
        t[j].x = fmaxf(t[j].x, 0.f);
        t[j].y = fmaxf(t[j].y, 0.f);
        t[j].z = fmaxf(t[j].z, 0.f);
        t[j].w = fmaxf(t[j].w, 0.f);
    }

    float4 h[16];
#pragma unroll
    for (int j = 0; j < 16; ++j) h[j] = make_float4(0.f, 0.f, 0.f, 0.f);

#pragma unroll
    for (int k = 0; k < OUT_DIM; ++k) {
        float4 tv = t[k / 4];
        float tk = ((k & 3) == 0) ? tv.x : ((k & 3) == 1) ? tv.y : ((k & 3) == 2) ? tv.z : tv.w;
        const float4* wr = W2v + (size_t)k * 16;
#pragma unroll
        for (int j = 0; j < 16; ++j) {
            float4 w = wr[j];
            h[j].x = fmaf(tk, w.x, h[j].x);
            h[j].y = fmaf(tk, w.y, h[j].y);
            h[j].z = fmaf(tk, w.z, h[j].z);
            h[j].w = fmaf(tk, w.w, h[j].w);
        }
    }

    const float4* brow = reinterpret_cast<const float4*>(base + (size_t)row * OUT_DIM);
    float4* orow = reinterpret_cast<float4*>(out + (size_t)row * OUT_DIM);
#pragma unroll
    for (int j = 0; j < 16; ++j) {
        float4 b = brow[j];
        float4 o;
        o.x = tanhf(b.x + h[j].x);
        o.y = tanhf(b.y + h[j].y);
        o.z = tanhf(b.z + h[j].z);
        o.w = tanhf(b.w + h[j].w);
        orow[j] = o;
    }
}

// ---------------------------------------------------------------------------
extern "C" void kernel_launch(void* const* d_in, const int* in_sizes, int n_in,
                              void* d_out, int out_size, void* d_ws, size_t ws_size,
                              hipStream_t stream)
{
    const float* feature = (const float*)d_in[0];
    const int*   src     = (const int*)d_in[1];
    const int*   dst     = (const int*)d_in[2];
    const float* W_lin   = (const float*)d_in[3];
    const float* W_d1    = (const float*)d_in[4];
    const float* W_d2    = (const float*)d_in[5];
    float* out = (float*)d_out;

    const size_t NODE_F = (size_t)N_NODES * OUT_DIM;   // 6.4M floats, 25.6 MB

    // Workspace: 3*25.6 MB + 0.8 MB + 12.8 MB ≈ 90 MB
    float* base = (float*)d_ws;
    float* u1   = base + NODE_F;
    float* m    = u1 + NODE_F;
    int*   H    = (int*)(m + NODE_F);                  // NBUCKETS*NBINBLK+1 ints
    int*   ebuf = H + ((size_t)NBUCKETS * NBINBLK + 1);// 3.2M ints

    int row_blocks = (N_NODES + 255) / 256;

    // iter 1 collapses: u0 == 0 -> m == 0 -> h == 0 -> u1 = tanh(feature@W_lin)
    gemm_base_tanh<<<row_blocks, 256, 0, stream>>>(feature, W_lin, base, u1);

    bin_hist   <<<NBINBLK, 256, 0, stream>>>(dst, H);
    bin_scan   <<<1, 1024, 0, stream>>>(H);
    bin_scatter<<<NBINBLK, 256, 0, stream>>>(src, dst, H, ebuf);

    bucket_gather<<<NBUCKETS, 256, 0, stream>>>(H, ebuf, u1, m);

    dense_tanh<<<row_blocks, 256, 0, stream>>>(m, W_d1, W_d2, base, out);
}

// Round 4
// 682.083 us; speedup vs baseline: 2.9669x; 2.9669x over previous
//
#include <hip/hip_runtime.h>
#include <math.h>

#define N_NODES 100000
#define N_EDGES 3200000
#define IN_DIM  128
#define OUT_DIM 64

#define BSHIFT   7
#define BNODES   128                                   // nodes per bucket
#define NBUCKETS ((N_NODES + BNODES - 1) / BNODES)     // 782
#define NBINBLK  128
#define CHUNK    (N_EDGES / NBINBLK)                   // 25000 (exact)
#define SEGCAP   6144                                  // max edges/bucket (mean 4092, sigma 64)

// ---------------------------------------------------------------------------
// Kernel 1: base = feature @ W_lin ; u1 = tanh(base)
// ---------------------------------------------------------------------------
__global__ __launch_bounds__(256) void gemm_base_tanh(
    const float* __restrict__ feature,
    const float* __restrict__ Wlin,
    float* __restrict__ base,
    float* __restrict__ u1)
{
    int row = blockIdx.x * 256 + threadIdx.x;
    if (row >= N_NODES) return;

    const float4* frow = reinterpret_cast<const float4*>(feature + (size_t)row * IN_DIM);
    const float4* Wv   = reinterpret_cast<const float4*>(Wlin);   // [IN_DIM][16] float4

    float4 acc[16];
#pragma unroll
    for (int j = 0; j < 16; ++j) acc[j] = make_float4(0.f, 0.f, 0.f, 0.f);

    for (int k4 = 0; k4 < IN_DIM / 4; ++k4) {
        float4 f = frow[k4];
#pragma unroll
        for (int kk = 0; kk < 4; ++kk) {
            float fk = (kk == 0) ? f.x : (kk == 1) ? f.y : (kk == 2) ? f.z : f.w;
            const float4* wr = Wv + (size_t)(k4 * 4 + kk) * (OUT_DIM / 4);
#pragma unroll
            for (int j = 0; j < 16; ++j) {
                float4 w = wr[j];
                acc[j].x = fmaf(fk, w.x, acc[j].x);
                acc[j].y = fmaf(fk, w.y, acc[j].y);
                acc[j].z = fmaf(fk, w.z, acc[j].z);
                acc[j].w = fmaf(fk, w.w, acc[j].w);
            }
        }
    }

    float4* brow = reinterpret_cast<float4*>(base + (size_t)row * OUT_DIM);
    float4* urow = reinterpret_cast<float4*>(u1   + (size_t)row * OUT_DIM);
#pragma unroll
    for (int j = 0; j < 16; ++j) {
        brow[j] = acc[j];
        float4 t;
        t.x = tanhf(acc[j].x);
        t.y = tanhf(acc[j].y);
        t.z = tanhf(acc[j].z);
        t.w = tanhf(acc[j].w);
        urow[j] = t;
    }
}

// ---------------------------------------------------------------------------
// Binning phase 1: per-block LDS histogram of dst>>7.  H bucket-major.
// ---------------------------------------------------------------------------
__global__ __launch_bounds__(256) void bin_hist(
    const int* __restrict__ dst, int* __restrict__ H)
{
    __shared__ int h[NBUCKETS];
    for (int k = threadIdx.x; k < NBUCKETS; k += 256) h[k] = 0;
    __syncthreads();

    int b = blockIdx.x;
    int beg = b * CHUNK, end = beg + CHUNK;
    for (int i = beg + threadIdx.x; i < end; i += 256)
        atomicAdd(&h[dst[i] >> BSHIFT], 1);
    __syncthreads();

    for (int k = threadIdx.x; k < NBUCKETS; k += 256)
        H[k * NBINBLK + b] = h[k];
}

__global__ __launch_bounds__(1024) void bin_scan(int* __restrict__ H)
{
    __shared__ int sums[1024];
    const int T = NBUCKETS * NBINBLK;          // 100096
    const int C = (T + 1023) / 1024;           // 98
    int t = threadIdx.x;
    int beg = t * C;
    int end = beg + C; if (end > T) end = T;
    if (beg > T) beg = T;

    int s = 0;
    for (int i = beg; i < end; ++i) s += H[i];
    sums[t] = s;
    __syncthreads();

    for (int off = 1; off < 1024; off <<= 1) {
        int v = (t >= off) ? sums[t - off] : 0;
        __syncthreads();
        sums[t] += v;
        __syncthreads();
    }

    int excl = (t == 0) ? 0 : sums[t - 1];
    for (int i = beg; i < end; ++i) { int v = H[i]; H[i] = excl; excl += v; }
    if (t == 1023) H[T] = sums[1023];          // == N_EDGES
}

__global__ __launch_bounds__(256) void bin_scatter(
    const int* __restrict__ src,
    const int* __restrict__ dst,
    const int* __restrict__ H,
    int* __restrict__ ebuf)
{
    __shared__ int cur[NBUCKETS];
    int b = blockIdx.x;
    for (int k = threadIdx.x; k < NBUCKETS; k += 256)
        cur[k] = H[k * NBINBLK + b];
    __syncthreads();

    int beg = b * CHUNK, end = beg + CHUNK;
    for (int i = beg + threadIdx.x; i < end; i += 256) {
        int d = dst[i];
        int k = d >> BSHIFT;
        int p = atomicAdd(&cur[k], 1);
        // pack: src (17 bits) | dlocal (7 bits) << 17
        ebuf[p] = src[i] | ((d & (BNODES - 1)) << 17);
    }
}

// ---------------------------------------------------------------------------
// Binning phase 2: per-bucket in-LDS counting sort by node.  Rewrites ebuf
// in place (src only, node-sorted) and emits exact per-node CSR offsets.
// All global writes are block-local regions -> no write amplification.
// ---------------------------------------------------------------------------
__global__ __launch_bounds__(256) void bucket_sort(
    const int* __restrict__ H,
    int* __restrict__ ebuf,
    int* __restrict__ node_off)
{
    __shared__ int seg[SEGCAP];
    __shared__ int cnt[BNODES];
    __shared__ int off[BNODES];
    int k = blockIdx.x;
    int beg = H[(size_t)k * NBINBLK];
    int end = H[(size_t)(k + 1) * NBINBLK];
    int n = end - beg;

    for (int j = threadIdx.x; j < BNODES; j += 256) cnt[j] = 0;
    __syncthreads();

    for (int i = threadIdx.x; i < n; i += 256) {
        int v = ebuf[beg + i];
        seg[i] = v;
        atomicAdd(&cnt[v >> 17], 1);
    }
    __syncthreads();

    if (threadIdx.x == 0) {
        int node0 = k * BNODES;
        int nvalid = N_NODES - node0; if (nvalid > BNODES) nvalid = BNODES;
        int excl = 0;
        for (int j = 0; j < nvalid; ++j) {
            off[j] = excl;
            node_off[node0 + j] = beg + excl;
            excl += cnt[j];
        }
        if (k == NBUCKETS - 1) node_off[N_NODES] = end;
    }
    __syncthreads();

    for (int i = threadIdx.x; i < n; i += 256) {
        int v = seg[i];
        int p = atomicAdd(&off[v >> 17], 1);
        ebuf[beg + p] = v & 0x1FFFF;
    }
}

// ---------------------------------------------------------------------------
// Gather: one wave per node.  Lane (q,c): q=lane>>4 handles edge-rows
// beg+q, beg+q+4, ...; c=lane&15 holds float4 column chunk.  16 rows in
// flight per wave (4-deep unroll x 4 quarters), register accumulate,
// shfl-xor cross-quarter reduce, one coalesced float4 store.  No atomics.
// ---------------------------------------------------------------------------
__global__ __launch_bounds__(256) void node_gather(
    const int* __restrict__ node_off,
    const int* __restrict__ csr,
    const float4* __restrict__ u1v,     // [N_NODES][16]
    float4* __restrict__ mv)            // [N_NODES][16]
{
    int wid = (blockIdx.x * 256 + threadIdx.x) >> 6;
    if (wid >= N_NODES) return;
    int lane = threadIdx.x & 63;
    int q = lane >> 4, c = lane & 15;

    int beg = node_off[wid];
    int end = node_off[wid + 1];

    float4 acc = make_float4(0.f, 0.f, 0.f, 0.f);
    int e = beg + q;
    for (; e + 12 < end; e += 16) {
        int s0 = csr[e];
        int s1 = csr[e + 4];
        int s2 = csr[e + 8];
        int s3 = csr[e + 12];
        float4 a = u1v[(size_t)s0 * 16 + c];
        float4 b = u1v[(size_t)s1 * 16 + c];
        float4 g = u1v[(size_t)s2 * 16 + c];
        float4 d = u1v[(size_t)s3 * 16 + c];
        acc.x += (a.x + b.x) + (g.x + d.x);
        acc.y += (a.y + b.y) + (g.y + d.y);
        acc.z += (a.z + b.z) + (g.z + d.z);
        acc.w += (a.w + b.w) + (g.w + d.w);
    }
    for (; e < end; e += 4) {
        int s = csr[e];
        float4 a = u1v[(size_t)s * 16 + c];
        acc.x += a.x; acc.y += a.y; acc.z += a.z; acc.w += a.w;
    }

    // reduce across the 4 quarters (lanes differing in bits 4,5)
    acc.x += __shfl_xor(acc.x, 16); acc.y += __shfl_xor(acc.y, 16);
    acc.z += __shfl_xor(acc.z, 16); acc.w += __shfl_xor(acc.w, 16);
    acc.x += __shfl_xor(acc.x, 32); acc.y += __shfl_xor(acc.y, 32);
    acc.z += __shfl_xor(acc.z, 32); acc.w += __shfl_xor(acc.w, 32);

    if (q == 0)
        mv[(size_t)wid * 16 + c] = acc;
}

// ---------------------------------------------------------------------------
// Kernel 3: out = tanh(base + relu(m @ W_d1) @ W_d2)
// ---------------------------------------------------------------------------
__global__ __launch_bounds__(256) void dense_tanh(
    const float* __restrict__ m,
    const float* __restrict__ W1,
    const float* __restrict__ W2,
    const float* __restrict__ base,
    float* __restrict__ out)
{
    int row = blockIdx.x * 256 + threadIdx.x;
    if (row >= N_NODES) return;

    const float4* mrow = reinterpret_cast<const float4*>(m + (size_t)row * OUT_DIM);
    const float4* W1v  = reinterpret_cast<const float4*>(W1);  // [64][16] float4
    const float4* W2v  = reinterpret_cast<const float4*>(W2);

    float4 t[16];
#pragma unroll
    for (int j = 0; j < 16; ++j) t[j] = make_float4(0.f, 0.f, 0.f, 0.f);

    for (int k4 = 0; k4 < OUT_DIM / 4; ++k4) {
        float4 mv = mrow[k4];
#pragma unroll
        for (int kk = 0; kk < 4; ++kk) {
            float mk = (kk == 0) ? mv.x : (kk == 1) ? mv.y : (kk == 2) ? mv.z : mv.w;
            const float4* wr = W1v + (size_t)(k4 * 4 + kk) * 16;
#pragma unroll
            for (int j = 0; j < 16; ++j) {
                float4 w = wr[j];
                t[j].x = fmaf(mk, w.x, t[j].x);
                t[j].y = fmaf(mk, w.y, t[j].y);
                t[j].z = fmaf(mk, w.z, t[j].z);
                t[j].w = fmaf(mk, w.w, t[j].w);
            }
        }
    }
#pragma unroll
    for (int j = 0; j < 16; ++j) {
        t[j].x = fmaxf(t[j].x, 0.f);
        t[j].y = fmaxf(t[j].y, 0.f);
        t[j].z = fmaxf(t[j].z, 0.f);
        t[j].w = fmaxf(t[j].w, 0.f);
    }

    float4 h[16];
#pragma unroll
    for (int j = 0; j < 16; ++j) h[j] = make_float4(0.f, 0.f, 0.f, 0.f);

#pragma unroll
    for (int k = 0; k < OUT_DIM; ++k) {
        float4 tv = t[k / 4];
        float tk = ((k & 3) == 0) ? tv.x : ((k & 3) == 1) ? tv.y : ((k & 3) == 2) ? tv.z : tv.w;
        const float4* wr = W2v + (size_t)k * 16;
#pragma unroll
        for (int j = 0; j < 16; ++j) {
            float4 w = wr[j];
            h[j].x = fmaf(tk, w.x, h[j].x);
            h[j].y = fmaf(tk, w.y, h[j].y);
            h[j].z = fmaf(tk, w.z, h[j].z);
            h[j].w = fmaf(tk, w.w, h[j].w);
        }
    }

    const float4* brow = reinterpret_cast<const float4*>(base + (size_t)row * OUT_DIM);
    float4* orow = reinterpret_cast<float4*>(out + (size_t)row * OUT_DIM);
#pragma unroll
    for (int j = 0; j < 16; ++j) {
        float4 b = brow[j];
        float4 o;
        o.x = tanhf(b.x + h[j].x);
        o.y = tanhf(b.y + h[j].y);
        o.z = tanhf(b.z + h[j].z);
        o.w = tanhf(b.w + h[j].w);
        orow[j] = o;
    }
}

// ---------------------------------------------------------------------------
extern "C" void kernel_launch(void* const* d_in, const int* in_sizes, int n_in,
                              void* d_out, int out_size, void* d_ws, size_t ws_size,
                              hipStream_t stream)
{
    const float* feature = (const float*)d_in[0];
    const int*   src     = (const int*)d_in[1];
    const int*   dst     = (const int*)d_in[2];
    const float* W_lin   = (const float*)d_in[3];
    const float* W_d1    = (const float*)d_in[4];
    const float* W_d2    = (const float*)d_in[5];
    float* out = (float*)d_out;

    const size_t NODE_F = (size_t)N_NODES * OUT_DIM;   // 6.4M floats, 25.6 MB

    // Workspace: 3*25.6 MB + ~0.8 MB + 12.8 MB ≈ 90.4 MB
    float* base     = (float*)d_ws;
    float* u1       = base + NODE_F;
    float* m        = u1 + NODE_F;
    int*   H        = (int*)(m + NODE_F);              // NBUCKETS*NBINBLK+1
    int*   node_off = H + ((size_t)NBUCKETS * NBINBLK + 4);  // N_NODES+1
    int*   ebuf     = node_off + (N_NODES + 4);        // 3.2M ints

    int row_blocks = (N_NODES + 255) / 256;

    // iter 1 collapses: u0 == 0 -> m == 0 -> h == 0 -> u1 = tanh(feature@W_lin)
    gemm_base_tanh<<<row_blocks, 256, 0, stream>>>(feature, W_lin, base, u1);

    bin_hist   <<<NBINBLK, 256, 0, stream>>>(dst, H);
    bin_scan   <<<1, 1024, 0, stream>>>(H);
    bin_scatter<<<NBINBLK, 256, 0, stream>>>(src, dst, H, ebuf);
    bucket_sort<<<NBUCKETS, 256, 0, stream>>>(H, ebuf, node_off);

    int gather_blocks = (int)(((size_t)N_NODES * 64 + 255) / 256);   // 25000
    node_gather<<<gather_blocks, 256, 0, stream>>>(
        node_off, ebuf, (const float4*)u1, (float4*)m);

    dense_tanh<<<row_blocks, 256, 0, stream>>>(m, W_d1, W_d2, base, out);
}

// Round 5
// 498.158 us; speedup vs baseline: 4.0624x; 1.3692x over previous
//
#include <hip/hip_runtime.h>
#include <math.h>

#define N_NODES 100000
#define N_EDGES 3200000
#define IN_DIM  128
#define OUT_DIM 64

#define BSHIFT   7
#define BNODES   128                                   // nodes per bucket
#define NBUCKETS ((N_NODES + BNODES - 1) / BNODES)     // 782
#define NBINBLK  128
#define CHUNK    (N_EDGES / NBINBLK)                   // 25000 (exact)
#define SEGCAP   6144                                  // max edges/bucket

__device__ __forceinline__ float rl(float v, int l) {
    return __int_as_float(__builtin_amdgcn_readlane(__float_as_int(v), l));
}

// ---------------------------------------------------------------------------
// Kernel 1: base = feature @ W_lin ; u1 = tanh(base)
// lane = output column; W_lin (128x64) resident in 128 VGPRs per lane;
// x broadcast via v_readlane. 2 rows in flight per wave. No loads in the
// MAC loop.
// ---------------------------------------------------------------------------
__global__ __launch_bounds__(256) void gemm_base_tanh(
    const float* __restrict__ feature,
    const float* __restrict__ Wlin,     // [128][64] row-major
    float* __restrict__ base,
    float* __restrict__ u1)
{
    int lane = threadIdx.x & 63;
    int wid  = (blockIdx.x * 256 + threadIdx.x) >> 6;
    int nw   = gridDim.x * 4;

    float w[IN_DIM];
#pragma unroll
    for (int k = 0; k < IN_DIM; ++k) w[k] = Wlin[k * OUT_DIM + lane];

    const int NPAIRS = N_NODES / 2;
    for (int p = wid; p < NPAIRS; p += nw) {
        int r0 = 2 * p, r1 = 2 * p + 1;
        float xa0 = feature[(size_t)r0 * IN_DIM + lane];
        float xa1 = feature[(size_t)r0 * IN_DIM + 64 + lane];
        float xb0 = feature[(size_t)r1 * IN_DIM + lane];
        float xb1 = feature[(size_t)r1 * IN_DIM + 64 + lane];

        float acc0 = 0.f, acc1 = 0.f;
#pragma unroll
        for (int k = 0; k < 64; ++k) {
            acc0 = fmaf(rl(xa0, k), w[k], acc0);
            acc1 = fmaf(rl(xb0, k), w[k], acc1);
        }
#pragma unroll
        for (int k = 0; k < 64; ++k) {
            acc0 = fmaf(rl(xa1, k), w[64 + k], acc0);
            acc1 = fmaf(rl(xb1, k), w[64 + k], acc1);
        }

        base[(size_t)r0 * OUT_DIM + lane] = acc0;
        base[(size_t)r1 * OUT_DIM + lane] = acc1;
        u1[(size_t)r0 * OUT_DIM + lane] = tanhf(acc0);
        u1[(size_t)r1 * OUT_DIM + lane] = tanhf(acc1);
    }
}

// ---------------------------------------------------------------------------
// Binning phase 1: per-block LDS histogram of dst>>7.  H bucket-major.
// ---------------------------------------------------------------------------
__global__ __launch_bounds__(256) void bin_hist(
    const int* __restrict__ dst, int* __restrict__ H)
{
    __shared__ int h[NBUCKETS];
    for (int k = threadIdx.x; k < NBUCKETS; k += 256) h[k] = 0;
    __syncthreads();

    int b = blockIdx.x;
    int beg = b * CHUNK, end = beg + CHUNK;
    for (int i = beg + threadIdx.x; i < end; i += 256)
        atomicAdd(&h[dst[i] >> BSHIFT], 1);
    __syncthreads();

    for (int k = threadIdx.x; k < NBUCKETS; k += 256)
        H[k * NBINBLK + b] = h[k];
}

__global__ __launch_bounds__(1024) void bin_scan(int* __restrict__ H)
{
    __shared__ int sums[1024];
    const int T = NBUCKETS * NBINBLK;          // 100096
    const int C = (T + 1023) / 1024;           // 98
    int t = threadIdx.x;
    int beg = t * C;
    int end = beg + C; if (end > T) end = T;
    if (beg > T) beg = T;

    int s = 0;
    for (int i = beg; i < end; ++i) s += H[i];
    sums[t] = s;
    __syncthreads();

    for (int off = 1; off < 1024; off <<= 1) {
        int v = (t >= off) ? sums[t - off] : 0;
        __syncthreads();
        sums[t] += v;
        __syncthreads();
    }

    int excl = (t == 0) ? 0 : sums[t - 1];
    for (int i = beg; i < end; ++i) { int v = H[i]; H[i] = excl; excl += v; }
    if (t == 1023) H[T] = sums[1023];          // == N_EDGES
}

__global__ __launch_bounds__(256) void bin_scatter(
    const int* __restrict__ src,
    const int* __restrict__ dst,
    const int* __restrict__ H,
    int* __restrict__ ebuf)
{
    __shared__ int cur[NBUCKETS];
    int b = blockIdx.x;
    for (int k = threadIdx.x; k < NBUCKETS; k += 256)
        cur[k] = H[k * NBINBLK + b];
    __syncthreads();

    int beg = b * CHUNK, end = beg + CHUNK;
    for (int i = beg + threadIdx.x; i < end; i += 256) {
        int d = dst[i];
        int k = d >> BSHIFT;
        int p = atomicAdd(&cur[k], 1);
        // pack: src (17 bits) | dlocal (7 bits) << 17
        ebuf[p] = src[i] | ((d & (BNODES - 1)) << 17);
    }
}

// ---------------------------------------------------------------------------
// Binning phase 2: per-bucket in-LDS counting sort by node.  Rewrites ebuf
// in place (src only, node-sorted) and emits exact per-node CSR offsets.
// ---------------------------------------------------------------------------
__global__ __launch_bounds__(256) void bucket_sort(
    const int* __restrict__ H,
    int* __restrict__ ebuf,
    int* __restrict__ node_off)
{
    __shared__ int seg[SEGCAP];
    __shared__ int cnt[BNODES];
    __shared__ int off[BNODES];
    int k = blockIdx.x;
    int beg = H[(size_t)k * NBINBLK];
    int end = H[(size_t)(k + 1) * NBINBLK];
    int n = end - beg;

    for (int j = threadIdx.x; j < BNODES; j += 256) cnt[j] = 0;
    __syncthreads();

    for (int i = threadIdx.x; i < n; i += 256) {
        int v = ebuf[beg + i];
        seg[i] = v;
        atomicAdd(&cnt[v >> 17], 1);
    }
    __syncthreads();

    if (threadIdx.x == 0) {
        int node0 = k * BNODES;
        int nvalid = N_NODES - node0; if (nvalid > BNODES) nvalid = BNODES;
        int excl = 0;
        for (int j = 0; j < nvalid; ++j) {
            off[j] = excl;
            node_off[node0 + j] = beg + excl;
            excl += cnt[j];
        }
        if (k == NBUCKETS - 1) node_off[N_NODES] = end;
    }
    __syncthreads();

    for (int i = threadIdx.x; i < n; i += 256) {
        int v = seg[i];
        int p = atomicAdd(&off[v >> 17], 1);
        ebuf[beg + p] = v & 0x1FFFF;
    }
}

// ---------------------------------------------------------------------------
// Gather: one wave per node, 16 u1-rows in flight, register accumulate,
// shfl-xor cross-quarter reduce, coalesced float4 store.  No atomics.
// ---------------------------------------------------------------------------
__global__ __launch_bounds__(256) void node_gather(
    const int* __restrict__ node_off,
    const int* __restrict__ csr,
    const float4* __restrict__ u1v,     // [N_NODES][16]
    float4* __restrict__ mv)            // [N_NODES][16]
{
    int wid = (blockIdx.x * 256 + threadIdx.x) >> 6;
    if (wid >= N_NODES) return;
    int lane = threadIdx.x & 63;
    int q = lane >> 4, c = lane & 15;

    int beg = node_off[wid];
    int end = node_off[wid + 1];

    float4 acc = make_float4(0.f, 0.f, 0.f, 0.f);
    int e = beg + q;
    for (; e + 12 < end; e += 16) {
        int s0 = csr[e];
        int s1 = csr[e + 4];
        int s2 = csr[e + 8];
        int s3 = csr[e + 12];
        float4 a = u1v[(size_t)s0 * 16 + c];
        float4 b = u1v[(size_t)s1 * 16 + c];
        float4 g = u1v[(size_t)s2 * 16 + c];
        float4 d = u1v[(size_t)s3 * 16 + c];
        acc.x += (a.x + b.x) + (g.x + d.x);
        acc.y += (a.y + b.y) + (g.y + d.y);
        acc.z += (a.z + b.z) + (g.z + d.z);
        acc.w += (a.w + b.w) + (g.w + d.w);
    }
    for (; e < end; e += 4) {
        int s = csr[e];
        float4 a = u1v[(size_t)s * 16 + c];
        acc.x += a.x; acc.y += a.y; acc.z += a.z; acc.w += a.w;
    }

    acc.x += __shfl_xor(acc.x, 16); acc.y += __shfl_xor(acc.y, 16);
    acc.z += __shfl_xor(acc.z, 16); acc.w += __shfl_xor(acc.w, 16);
    acc.x += __shfl_xor(acc.x, 32); acc.y += __shfl_xor(acc.y, 32);
    acc.z += __shfl_xor(acc.z, 32); acc.w += __shfl_xor(acc.w, 32);

    if (q == 0)
        mv[(size_t)wid * 16 + c] = acc;
}

// ---------------------------------------------------------------------------
// Kernel 3: out = tanh(base + relu(m @ W_d1) @ W_d2)
// lane = column; W_d1/W_d2 resident in 64+64 VGPRs; x via readlane.
// Layer-2 input t is already lane-resident (zero memory traffic).
// ---------------------------------------------------------------------------
__global__ __launch_bounds__(256) void dense_tanh(
    const float* __restrict__ m,
    const float* __restrict__ W1,       // [64][64]
    const float* __restrict__ W2,       // [64][64]
    const float* __restrict__ base,
    float* __restrict__ out)
{
    int lane = threadIdx.x & 63;
    int wid  = (blockIdx.x * 256 + threadIdx.x) >> 6;
    int nw   = gridDim.x * 4;

    float w1[64], w2[64];
#pragma unroll
    for (int k = 0; k < 64; ++k) w1[k] = W1[k * 64 + lane];
#pragma unroll
    for (int k = 0; k < 64; ++k) w2[k] = W2[k * 64 + lane];

    const int NPAIRS = N_NODES / 2;
    for (int p = wid; p < NPAIRS; p += nw) {
        int r0 = 2 * p, r1 = 2 * p + 1;
        float x0 = m[(size_t)r0 * 64 + lane];
        float x1 = m[(size_t)r1 * 64 + lane];

        float a0 = 0.f, a1 = 0.f;
#pragma unroll
        for (int k = 0; k < 64; ++k) {
            a0 = fmaf(rl(x0, k), w1[k], a0);
            a1 = fmaf(rl(x1, k), w1[k], a1);
        }
        float t0 = fmaxf(a0, 0.f);
        float t1 = fmaxf(a1, 0.f);

        float h0 = 0.f, h1 = 0.f;
#pragma unroll
        for (int k = 0; k < 64; ++k) {
            h0 = fmaf(rl(t0, k), w2[k], h0);
            h1 = fmaf(rl(t1, k), w2[k], h1);
        }

        float b0 = base[(size_t)r0 * 64 + lane];
        float b1 = base[(size_t)r1 * 64 + lane];
        out[(size_t)r0 * 64 + lane] = tanhf(b0 + h0);
        out[(size_t)r1 * 64 + lane] = tanhf(b1 + h1);
    }
}

// ---------------------------------------------------------------------------
extern "C" void kernel_launch(void* const* d_in, const int* in_sizes, int n_in,
                              void* d_out, int out_size, void* d_ws, size_t ws_size,
                              hipStream_t stream)
{
    const float* feature = (const float*)d_in[0];
    const int*   src     = (const int*)d_in[1];
    const int*   dst     = (const int*)d_in[2];
    const float* W_lin   = (const float*)d_in[3];
    const float* W_d1    = (const float*)d_in[4];
    const float* W_d2    = (const float*)d_in[5];
    float* out = (float*)d_out;

    const size_t NODE_F = (size_t)N_NODES * OUT_DIM;   // 6.4M floats, 25.6 MB

    float* base     = (float*)d_ws;
    float* u1       = base + NODE_F;
    float* m        = u1 + NODE_F;
    int*   H        = (int*)(m + NODE_F);              // NBUCKETS*NBINBLK+1
    int*   node_off = H + ((size_t)NBUCKETS * NBINBLK + 4);  // N_NODES+1
    int*   ebuf     = node_off + (N_NODES + 4);        // 3.2M ints

    // iter 1 collapses: u0 == 0 -> m == 0 -> h == 0 -> u1 = tanh(feature@W_lin)
    gemm_base_tanh<<<1024, 256, 0, stream>>>(feature, W_lin, base, u1);

    bin_hist   <<<NBINBLK, 256, 0, stream>>>(dst, H);
    bin_scan   <<<1, 1024, 0, stream>>>(H);
    bin_scatter<<<NBINBLK, 256, 0, stream>>>(src, dst, H, ebuf);
    bucket_sort<<<NBUCKETS, 256, 0, stream>>>(H, ebuf, node_off);

    int gather_blocks = (int)(((size_t)N_NODES * 64 + 255) / 256);   // 25000
    node_gather<<<gather_blocks, 256, 0, stream>>>(
        node_off, ebuf, (const float4*)u1, (float4*)m);

    dense_tanh<<<1024, 256, 0, stream>>>(m, W_d1, W_d2, base, out);
}

// Round 6
// 345.246 us; speedup vs baseline: 5.8616x; 1.4429x over previous
//
#include <hip/hip_runtime.h>
#include <math.h>

#define N_NODES 100000
#define N_EDGES 3200000
#define IN_DIM  128
#define OUT_DIM 64

#define BSHIFT   7
#define BNODES   128                                   // nodes per bucket
#define NBUCKETS ((N_NODES + BNODES - 1) / BNODES)     // 782
#define NBINBLK  128
#define CHUNK    (N_EDGES / NBINBLK)                   // 25000 (exact)
#define SEGCAP   6144                                  // max edges/bucket

__device__ __forceinline__ float rl(float v, int l) {
    return __int_as_float(__builtin_amdgcn_readlane(__float_as_int(v), l));
}

// ---------------------------------------------------------------------------
// Kernel 1: base = feature @ W_lin ; u1 = tanh(base)
// lane = output column; W_lin (128x64) resident in 128 VGPRs per lane;
// x broadcast via v_readlane. 2 rows in flight per wave.
// ---------------------------------------------------------------------------
__global__ __launch_bounds__(256) void gemm_base_tanh(
    const float* __restrict__ feature,
    const float* __restrict__ Wlin,     // [128][64] row-major
    float* __restrict__ base,
    float* __restrict__ u1)
{
    int lane = threadIdx.x & 63;
    int wid  = (blockIdx.x * 256 + threadIdx.x) >> 6;
    int nw   = gridDim.x * 4;

    float w[IN_DIM];
#pragma unroll
    for (int k = 0; k < IN_DIM; ++k) w[k] = Wlin[k * OUT_DIM + lane];

    const int NPAIRS = N_NODES / 2;
    for (int p = wid; p < NPAIRS; p += nw) {
        int r0 = 2 * p, r1 = 2 * p + 1;
        float xa0 = feature[(size_t)r0 * IN_DIM + lane];
        float xa1 = feature[(size_t)r0 * IN_DIM + 64 + lane];
        float xb0 = feature[(size_t)r1 * IN_DIM + lane];
        float xb1 = feature[(size_t)r1 * IN_DIM + 64 + lane];

        float acc0 = 0.f, acc1 = 0.f;
#pragma unroll
        for (int k = 0; k < 64; ++k) {
            acc0 = fmaf(rl(xa0, k), w[k], acc0);
            acc1 = fmaf(rl(xb0, k), w[k], acc1);
        }
#pragma unroll
        for (int k = 0; k < 64; ++k) {
            acc0 = fmaf(rl(xa1, k), w[64 + k], acc0);
            acc1 = fmaf(rl(xb1, k), w[64 + k], acc1);
        }

        base[(size_t)r0 * OUT_DIM + lane] = acc0;
        base[(size_t)r1 * OUT_DIM + lane] = acc1;
        u1[(size_t)r0 * OUT_DIM + lane] = tanhf(acc0);
        u1[(size_t)r1 * OUT_DIM + lane] = tanhf(acc1);
    }
}

// ---------------------------------------------------------------------------
// Binning phase 1: per-block LDS histogram of dst>>7.  H bucket-major.
// ---------------------------------------------------------------------------
__global__ __launch_bounds__(256) void bin_hist(
    const int* __restrict__ dst, int* __restrict__ H)
{
    __shared__ int h[NBUCKETS];
    for (int k = threadIdx.x; k < NBUCKETS; k += 256) h[k] = 0;
    __syncthreads();

    int b = blockIdx.x;
    int beg = b * CHUNK, end = beg + CHUNK;
    for (int i = beg + threadIdx.x; i < end; i += 256)
        atomicAdd(&h[dst[i] >> BSHIFT], 1);
    __syncthreads();

    for (int k = threadIdx.x; k < NBUCKETS; k += 256)
        H[k * NBINBLK + b] = h[k];
}

// ---------------------------------------------------------------------------
// Hierarchical scan of H (bucket-major, NBUCKETS x NBINBLK), bit-exact:
//   scan_local: per-bucket exclusive scan of 128 entries + bucket total
//   scan_tot:   exclusive scan of 782 bucket totals
//   add_base:   H[k][b] += base[k];  H[T] = N_EDGES
// ---------------------------------------------------------------------------
__global__ __launch_bounds__(NBINBLK) void scan_local(
    int* __restrict__ H, int* __restrict__ Btot)
{
    __shared__ int s[NBINBLK];
    int k = blockIdx.x, t = threadIdx.x;
    int v = H[(size_t)k * NBINBLK + t];
    s[t] = v;
    __syncthreads();
#pragma unroll
    for (int off = 1; off < NBINBLK; off <<= 1) {
        int x = (t >= off) ? s[t - off] : 0;
        __syncthreads();
        s[t] += x;
        __syncthreads();
    }
    H[(size_t)k * NBINBLK + t] = s[t] - v;      // exclusive
    if (t == NBINBLK - 1) Btot[k] = s[t];       // inclusive total
}

__global__ __launch_bounds__(1024) void scan_tot(int* __restrict__ Btot)
{
    __shared__ int s[1024];
    int t = threadIdx.x;
    int v = (t < NBUCKETS) ? Btot[t] : 0;
    s[t] = v;
    __syncthreads();
#pragma unroll
    for (int off = 1; off < 1024; off <<= 1) {
        int x = (t >= off) ? s[t - off] : 0;
        __syncthreads();
        s[t] += x;
        __syncthreads();
    }
    if (t < NBUCKETS) Btot[t] = s[t] - v;       // exclusive bucket base
}

__global__ __launch_bounds__(NBINBLK) void add_base(
    int* __restrict__ H, const int* __restrict__ Btot)
{
    int k = blockIdx.x, t = threadIdx.x;
    H[(size_t)k * NBINBLK + t] += Btot[k];
    if (k == 0 && t == 0) H[(size_t)NBUCKETS * NBINBLK] = N_EDGES;
}

// ---------------------------------------------------------------------------
__global__ __launch_bounds__(256) void bin_scatter(
    const int* __restrict__ src,
    const int* __restrict__ dst,
    const int* __restrict__ H,
    int* __restrict__ ebuf)
{
    __shared__ int cur[NBUCKETS];
    int b = blockIdx.x;
    for (int k = threadIdx.x; k < NBUCKETS; k += 256)
        cur[k] = H[k * NBINBLK + b];
    __syncthreads();

    int beg = b * CHUNK, end = beg + CHUNK;
    for (int i = beg + threadIdx.x; i < end; i += 256) {
        int d = dst[i];
        int k = d >> BSHIFT;
        int p = atomicAdd(&cur[k], 1);
        // pack: src (17 bits) | dlocal (7 bits) << 17
        ebuf[p] = src[i] | ((d & (BNODES - 1)) << 17);
    }
}

// ---------------------------------------------------------------------------
// Binning phase 2: per-bucket in-LDS counting sort by node.  Rewrites ebuf
// in place (src only, node-sorted) and emits exact per-node CSR offsets.
// ---------------------------------------------------------------------------
__global__ __launch_bounds__(256) void bucket_sort(
    const int* __restrict__ H,
    int* __restrict__ ebuf,
    int* __restrict__ node_off)
{
    __shared__ int seg[SEGCAP];
    __shared__ int cnt[BNODES];
    __shared__ int off[BNODES];
    int k = blockIdx.x;
    int beg = H[(size_t)k * NBINBLK];
    int end = H[(size_t)(k + 1) * NBINBLK];
    int n = end - beg;

    for (int j = threadIdx.x; j < BNODES; j += 256) cnt[j] = 0;
    __syncthreads();

    for (int i = threadIdx.x; i < n; i += 256) {
        int v = ebuf[beg + i];
        seg[i] = v;
        atomicAdd(&cnt[v >> 17], 1);
    }
    __syncthreads();

    if (threadIdx.x == 0) {
        int node0 = k * BNODES;
        int nvalid = N_NODES - node0; if (nvalid > BNODES) nvalid = BNODES;
        int excl = 0;
        for (int j = 0; j < nvalid; ++j) {
            off[j] = excl;
            node_off[node0 + j] = beg + excl;
            excl += cnt[j];
        }
        if (k == NBUCKETS - 1) node_off[N_NODES] = end;
    }
    __syncthreads();

    for (int i = threadIdx.x; i < n; i += 256) {
        int v = seg[i];
        int p = atomicAdd(&off[v >> 17], 1);
        ebuf[beg + p] = v & 0x1FFFF;
    }
}

// ---------------------------------------------------------------------------
// Gather: one wave per node, 16 u1-rows in flight, register accumulate,
// shfl-xor cross-quarter reduce, coalesced float4 store.  No atomics.
// ---------------------------------------------------------------------------
__global__ __launch_bounds__(256) void node_gather(
    const int* __restrict__ node_off,
    const int* __restrict__ csr,
    const float4* __restrict__ u1v,     // [N_NODES][16]
    float4* __restrict__ mv)            // [N_NODES][16]
{
    int wid = (blockIdx.x * 256 + threadIdx.x) >> 6;
    if (wid >= N_NODES) return;
    int lane = threadIdx.x & 63;
    int q = lane >> 4, c = lane & 15;

    int beg = node_off[wid];
    int end = node_off[wid + 1];

    float4 acc = make_float4(0.f, 0.f, 0.f, 0.f);
    int e = beg + q;
    for (; e + 12 < end; e += 16) {
        int s0 = csr[e];
        int s1 = csr[e + 4];
        int s2 = csr[e + 8];
        int s3 = csr[e + 12];
        float4 a = u1v[(size_t)s0 * 16 + c];
        float4 b = u1v[(size_t)s1 * 16 + c];
        float4 g = u1v[(size_t)s2 * 16 + c];
        float4 d = u1v[(size_t)s3 * 16 + c];
        acc.x += (a.x + b.x) + (g.x + d.x);
        acc.y += (a.y + b.y) + (g.y + d.y);
        acc.z += (a.z + b.z) + (g.z + d.z);
        acc.w += (a.w + b.w) + (g.w + d.w);
    }
    for (; e < end; e += 4) {
        int s = csr[e];
        float4 a = u1v[(size_t)s * 16 + c];
        acc.x += a.x; acc.y += a.y; acc.z += a.z; acc.w += a.w;
    }

    acc.x += __shfl_xor(acc.x, 16); acc.y += __shfl_xor(acc.y, 16);
    acc.z += __shfl_xor(acc.z, 16); acc.w += __shfl_xor(acc.w, 16);
    acc.x += __shfl_xor(acc.x, 32); acc.y += __shfl_xor(acc.y, 32);
    acc.z += __shfl_xor(acc.z, 32); acc.w += __shfl_xor(acc.w, 32);

    if (q == 0)
        mv[(size_t)wid * 16 + c] = acc;
}

// ---------------------------------------------------------------------------
// Kernel 3: out = tanh(base + relu(m @ W_d1) @ W_d2)
// lane = column; W_d1/W_d2 resident in 64+64 VGPRs; x via readlane.
// ---------------------------------------------------------------------------
__global__ __launch_bounds__(256) void dense_tanh(
    const float* __restrict__ m,
    const float* __restrict__ W1,       // [64][64]
    const float* __restrict__ W2,       // [64][64]
    const float* __restrict__ base,
    float* __restrict__ out)
{
    int lane = threadIdx.x & 63;
    int wid  = (blockIdx.x * 256 + threadIdx.x) >> 6;
    int nw   = gridDim.x * 4;

    float w1[64], w2[64];
#pragma unroll
    for (int k = 0; k < 64; ++k) w1[k] = W1[k * 64 + lane];
#pragma unroll
    for (int k = 0; k < 64; ++k) w2[k] = W2[k * 64 + lane];

    const int NPAIRS = N_NODES / 2;
    for (int p = wid; p < NPAIRS; p += nw) {
        int r0 = 2 * p, r1 = 2 * p + 1;
        float x0 = m[(size_t)r0 * 64 + lane];
        float x1 = m[(size_t)r1 * 64 + lane];

        float a0 = 0.f, a1 = 0.f;
#pragma unroll
        for (int k = 0; k < 64; ++k) {
            a0 = fmaf(rl(x0, k), w1[k], a0);
            a1 = fmaf(rl(x1, k), w1[k], a1);
        }
        float t0 = fmaxf(a0, 0.f);
        float t1 = fmaxf(a1, 0.f);

        float h0 = 0.f, h1 = 0.f;
#pragma unroll
        for (int k = 0; k < 64; ++k) {
            h0 = fmaf(rl(t0, k), w2[k], h0);
            h1 = fmaf(rl(t1, k), w2[k], h1);
        }

        float b0 = base[(size_t)r0 * 64 + lane];
        float b1 = base[(size_t)r1 * 64 + lane];
        out[(size_t)r0 * 64 + lane] = tanhf(b0 + h0);
        out[(size_t)r1 * 64 + lane] = tanhf(b1 + h1);
    }
}

// ---------------------------------------------------------------------------
extern "C" void kernel_launch(void* const* d_in, const int* in_sizes, int n_in,
                              void* d_out, int out_size, void* d_ws, size_t ws_size,
                              hipStream_t stream)
{
    const float* feature = (const float*)d_in[0];
    const int*   src     = (const int*)d_in[1];
    const int*   dst     = (const int*)d_in[2];
    const float* W_lin   = (const float*)d_in[3];
    const float* W_d1    = (const float*)d_in[4];
    const float* W_d2    = (const float*)d_in[5];
    float* out = (float*)d_out;

    const size_t NODE_F = (size_t)N_NODES * OUT_DIM;   // 6.4M floats, 25.6 MB

    float* base     = (float*)d_ws;
    float* u1       = base + NODE_F;
    float* m        = u1 + NODE_F;
    int*   H        = (int*)(m + NODE_F);              // NBUCKETS*NBINBLK+1
    int*   Btot     = H + ((size_t)NBUCKETS * NBINBLK + 4);  // NBUCKETS
    int*   node_off = Btot + (NBUCKETS + 4);           // N_NODES+1
    int*   ebuf     = node_off + (N_NODES + 4);        // 3.2M ints

    // iter 1 collapses: u0 == 0 -> m == 0 -> h == 0 -> u1 = tanh(feature@W_lin)
    gemm_base_tanh<<<1024, 256, 0, stream>>>(feature, W_lin, base, u1);

    bin_hist  <<<NBINBLK, 256, 0, stream>>>(dst, H);
    scan_local<<<NBUCKETS, NBINBLK, 0, stream>>>(H, Btot);
    scan_tot  <<<1, 1024, 0, stream>>>(Btot);
    add_base  <<<NBUCKETS, NBINBLK, 0, stream>>>(H, Btot);
    bin_scatter<<<NBINBLK, 256, 0, stream>>>(src, dst, H, ebuf);
    bucket_sort<<<NBUCKETS, 256, 0, stream>>>(H, ebuf, node_off);

    int gather_blocks = (int)(((size_t)N_NODES * 64 + 255) / 256);   // 25000
    node_gather<<<gather_blocks, 256, 0, stream>>>(
        node_off, ebuf, (const float4*)u1, (float4*)m);

    dense_tanh<<<1024, 256, 0, stream>>>(m, W_d1, W_d2, base, out);
}

// Round 7
// 296.363 us; speedup vs baseline: 6.8285x; 1.1649x over previous
//
#include <hip/hip_runtime.h>
#include <math.h>

#define N_NODES 100000
#define N_EDGES 3200000
#define IN_DIM  128
#define OUT_DIM 64

#define BSHIFT   7
#define BNODES   128                                   // nodes per bucket
#define NBUCKETS ((N_NODES + BNODES - 1) / BNODES)     // 782
#define NBINBLK  128
#define CHUNK    (N_EDGES / NBINBLK)                   // 25000 (exact)
#define SEGCAP   6144                                  // max edges/bucket

typedef _Float16 half8 __attribute__((ext_vector_type(8)));

__device__ __forceinline__ float rl(float v, int l) {
    return __int_as_float(__builtin_amdgcn_readlane(__float_as_int(v), l));
}

// ---------------------------------------------------------------------------
// Kernel 1: base = feature @ W_lin (fp32) ; u1 = tanh(base) stored as fp16.
// lane = output column; W_lin resident in 128 VGPRs; x via v_readlane.
// ---------------------------------------------------------------------------
__global__ __launch_bounds__(256) void gemm_base_tanh(
    const float* __restrict__ feature,
    const float* __restrict__ Wlin,     // [128][64] row-major
    float* __restrict__ base,
    _Float16* __restrict__ u1h)
{
    int lane = threadIdx.x & 63;
    int wid  = (blockIdx.x * 256 + threadIdx.x) >> 6;
    int nw   = gridDim.x * 4;

    float w[IN_DIM];
#pragma unroll
    for (int k = 0; k < IN_DIM; ++k) w[k] = Wlin[k * OUT_DIM + lane];

    const int NPAIRS = N_NODES / 2;
    for (int p = wid; p < NPAIRS; p += nw) {
        int r0 = 2 * p, r1 = 2 * p + 1;
        float xa0 = feature[(size_t)r0 * IN_DIM + lane];
        float xa1 = feature[(size_t)r0 * IN_DIM + 64 + lane];
        float xb0 = feature[(size_t)r1 * IN_DIM + lane];
        float xb1 = feature[(size_t)r1 * IN_DIM + 64 + lane];

        float acc0 = 0.f, acc1 = 0.f;
#pragma unroll
        for (int k = 0; k < 64; ++k) {
            acc0 = fmaf(rl(xa0, k), w[k], acc0);
            acc1 = fmaf(rl(xb0, k), w[k], acc1);
        }
#pragma unroll
        for (int k = 0; k < 64; ++k) {
            acc0 = fmaf(rl(xa1, k), w[64 + k], acc0);
            acc1 = fmaf(rl(xb1, k), w[64 + k], acc1);
        }

        base[(size_t)r0 * OUT_DIM + lane] = acc0;
        base[(size_t)r1 * OUT_DIM + lane] = acc1;
        u1h[(size_t)r0 * OUT_DIM + lane] = (_Float16)tanhf(acc0);
        u1h[(size_t)r1 * OUT_DIM + lane] = (_Float16)tanhf(acc1);
    }
}

// ---------------------------------------------------------------------------
// Binning phase 1: per-block LDS histogram of dst>>7.  H bucket-major.
// ---------------------------------------------------------------------------
__global__ __launch_bounds__(256) void bin_hist(
    const int* __restrict__ dst, int* __restrict__ H)
{
    __shared__ int h[NBUCKETS];
    for (int k = threadIdx.x; k < NBUCKETS; k += 256) h[k] = 0;
    __syncthreads();

    int b = blockIdx.x;
    int beg = b * CHUNK, end = beg + CHUNK;
    for (int i = beg + threadIdx.x; i < end; i += 256)
        atomicAdd(&h[dst[i] >> BSHIFT], 1);
    __syncthreads();

    for (int k = threadIdx.x; k < NBUCKETS; k += 256)
        H[k * NBINBLK + b] = h[k];
}

// ---------------------------------------------------------------------------
// Hierarchical scan of H (bucket-major), bit-exact.
// ---------------------------------------------------------------------------
__global__ __launch_bounds__(NBINBLK) void scan_local(
    int* __restrict__ H, int* __restrict__ Btot)
{
    __shared__ int s[NBINBLK];
    int k = blockIdx.x, t = threadIdx.x;
    int v = H[(size_t)k * NBINBLK + t];
    s[t] = v;
    __syncthreads();
#pragma unroll
    for (int off = 1; off < NBINBLK; off <<= 1) {
        int x = (t >= off) ? s[t - off] : 0;
        __syncthreads();
        s[t] += x;
        __syncthreads();
    }
    H[(size_t)k * NBINBLK + t] = s[t] - v;      // exclusive
    if (t == NBINBLK - 1) Btot[k] = s[t];       // inclusive total
}

__global__ __launch_bounds__(1024) void scan_tot(int* __restrict__ Btot)
{
    __shared__ int s[1024];
    int t = threadIdx.x;
    int v = (t < NBUCKETS) ? Btot[t] : 0;
    s[t] = v;
    __syncthreads();
#pragma unroll
    for (int off = 1; off < 1024; off <<= 1) {
        int x = (t >= off) ? s[t - off] : 0;
        __syncthreads();
        s[t] += x;
        __syncthreads();
    }
    if (t < NBUCKETS) Btot[t] = s[t] - v;       // exclusive bucket base
}

__global__ __launch_bounds__(NBINBLK) void add_base(
    int* __restrict__ H, const int* __restrict__ Btot)
{
    int k = blockIdx.x, t = threadIdx.x;
    H[(size_t)k * NBINBLK + t] += Btot[k];
    if (k == 0 && t == 0) H[(size_t)NBUCKETS * NBINBLK] = N_EDGES;
}

// ---------------------------------------------------------------------------
__global__ __launch_bounds__(256) void bin_scatter(
    const int* __restrict__ src,
    const int* __restrict__ dst,
    const int* __restrict__ H,
    int* __restrict__ ebuf)
{
    __shared__ int cur[NBUCKETS];
    int b = blockIdx.x;
    for (int k = threadIdx.x; k < NBUCKETS; k += 256)
        cur[k] = H[k * NBINBLK + b];
    __syncthreads();

    int beg = b * CHUNK, end = beg + CHUNK;
    for (int i = beg + threadIdx.x; i < end; i += 256) {
        int d = dst[i];
        int k = d >> BSHIFT;
        int p = atomicAdd(&cur[k], 1);
        // pack: src (17 bits) | dlocal (7 bits) << 17
        ebuf[p] = src[i] | ((d & (BNODES - 1)) << 17);
    }
}

// ---------------------------------------------------------------------------
// Binning phase 2: per-bucket in-LDS counting sort by node.  Rewrites ebuf
// in place (src only, node-sorted) and emits exact per-node CSR offsets.
// ---------------------------------------------------------------------------
__global__ __launch_bounds__(256) void bucket_sort(
    const int* __restrict__ H,
    int* __restrict__ ebuf,
    int* __restrict__ node_off)
{
    __shared__ int seg[SEGCAP];
    __shared__ int cnt[BNODES];
    __shared__ int off[BNODES];
    int k = blockIdx.x;
    int beg = H[(size_t)k * NBINBLK];
    int end = H[(size_t)(k + 1) * NBINBLK];
    int n = end - beg;

    for (int j = threadIdx.x; j < BNODES; j += 256) cnt[j] = 0;
    __syncthreads();

    for (int i = threadIdx.x; i < n; i += 256) {
        int v = ebuf[beg + i];
        seg[i] = v;
        atomicAdd(&cnt[v >> 17], 1);
    }
    __syncthreads();

    if (threadIdx.x == 0) {
        int node0 = k * BNODES;
        int nvalid = N_NODES - node0; if (nvalid > BNODES) nvalid = BNODES;
        int excl = 0;
        for (int j = 0; j < nvalid; ++j) {
            off[j] = excl;
            node_off[node0 + j] = beg + excl;
            excl += cnt[j];
        }
        if (k == NBUCKETS - 1) node_off[N_NODES] = end;
    }
    __syncthreads();

    for (int i = threadIdx.x; i < n; i += 256) {
        int v = seg[i];
        int p = atomicAdd(&off[v >> 17], 1);
        ebuf[beg + p] = v & 0x1FFFF;
    }
}

// ---------------------------------------------------------------------------
// Gather: one wave per node over fp16 u1 rows (128 B each).
// lane (q,c): q=lane>>3 = edge slot (8 edges/wave-step), c=lane&7 = 16 B
// half8 column chunk.  4-deep unroll -> 32 edges in flight per wave.
// fp32 register accumulate, shfl-xor(8,16,32) reduce, 256 B coalesced store.
// ---------------------------------------------------------------------------
__global__ __launch_bounds__(256) void node_gather(
    const int* __restrict__ node_off,
    const int* __restrict__ csr,
    const half8* __restrict__ u1v,      // [N_NODES][8]
    float* __restrict__ m)
{
    int wid = (blockIdx.x * 256 + threadIdx.x) >> 6;
    if (wid >= N_NODES) return;
    int lane = threadIdx.x & 63;
    int q = lane >> 3, c = lane & 7;

    int beg = node_off[wid];
    int end = node_off[wid + 1];

    float acc[8];
#pragma unroll
    for (int i = 0; i < 8; ++i) acc[i] = 0.f;

    int e = beg + q;
    for (; e + 24 < end; e += 32) {
        int s0 = csr[e];
        int s1 = csr[e + 8];
        int s2 = csr[e + 16];
        int s3 = csr[e + 24];
        half8 a = u1v[(size_t)s0 * 8 + c];
        half8 b = u1v[(size_t)s1 * 8 + c];
        half8 g = u1v[(size_t)s2 * 8 + c];
        half8 d = u1v[(size_t)s3 * 8 + c];
#pragma unroll
        for (int i = 0; i < 8; ++i)
            acc[i] += ((float)a[i] + (float)b[i]) + ((float)g[i] + (float)d[i]);
    }
    for (; e < end; e += 8) {
        half8 a = u1v[(size_t)csr[e] * 8 + c];
#pragma unroll
        for (int i = 0; i < 8; ++i) acc[i] += (float)a[i];
    }

    // reduce across the 8 q-groups (lane bits 3,4,5)
#pragma unroll
    for (int i = 0; i < 8; ++i) {
        acc[i] += __shfl_xor(acc[i], 8);
        acc[i] += __shfl_xor(acc[i], 16);
        acc[i] += __shfl_xor(acc[i], 32);
    }

    if (q == 0) {
        float4* mr = reinterpret_cast<float4*>(m + (size_t)wid * OUT_DIM + c * 8);
        mr[0] = make_float4(acc[0], acc[1], acc[2], acc[3]);
        mr[1] = make_float4(acc[4], acc[5], acc[6], acc[7]);
    }
}

// ---------------------------------------------------------------------------
// Kernel 3: out = tanh(base + relu(m @ W_d1) @ W_d2)
// lane = column; W_d1/W_d2 resident in 64+64 VGPRs; x via readlane.
// ---------------------------------------------------------------------------
__global__ __launch_bounds__(256) void dense_tanh(
    const float* __restrict__ m,
    const float* __restrict__ W1,       // [64][64]
    const float* __restrict__ W2,       // [64][64]
    const float* __restrict__ base,
    float* __restrict__ out)
{
    int lane = threadIdx.x & 63;
    int wid  = (blockIdx.x * 256 + threadIdx.x) >> 6;
    int nw   = gridDim.x * 4;

    float w1[64], w2[64];
#pragma unroll
    for (int k = 0; k < 64; ++k) w1[k] = W1[k * 64 + lane];
#pragma unroll
    for (int k = 0; k < 64; ++k) w2[k] = W2[k * 64 + lane];

    const int NPAIRS = N_NODES / 2;
    for (int p = wid; p < NPAIRS; p += nw) {
        int r0 = 2 * p, r1 = 2 * p + 1;
        float x0 = m[(size_t)r0 * 64 + lane];
        float x1 = m[(size_t)r1 * 64 + lane];

        float a0 = 0.f, a1 = 0.f;
#pragma unroll
        for (int k = 0; k < 64; ++k) {
            a0 = fmaf(rl(x0, k), w1[k], a0);
            a1 = fmaf(rl(x1, k), w1[k], a1);
        }
        float t0 = fmaxf(a0, 0.f);
        float t1 = fmaxf(a1, 0.f);

        float h0 = 0.f, h1 = 0.f;
#pragma unroll
        for (int k = 0; k < 64; ++k) {
            h0 = fmaf(rl(t0, k), w2[k], h0);
            h1 = fmaf(rl(t1, k), w2[k], h1);
        }

        float b0 = base[(size_t)r0 * 64 + lane];
        float b1 = base[(size_t)r1 * 64 + lane];
        out[(size_t)r0 * 64 + lane] = tanhf(b0 + h0);
        out[(size_t)r1 * 64 + lane] = tanhf(b1 + h1);
    }
}

// ---------------------------------------------------------------------------
extern "C" void kernel_launch(void* const* d_in, const int* in_sizes, int n_in,
                              void* d_out, int out_size, void* d_ws, size_t ws_size,
                              hipStream_t stream)
{
    const float* feature = (const float*)d_in[0];
    const int*   src     = (const int*)d_in[1];
    const int*   dst     = (const int*)d_in[2];
    const float* W_lin   = (const float*)d_in[3];
    const float* W_d1    = (const float*)d_in[4];
    const float* W_d2    = (const float*)d_in[5];
    float* out = (float*)d_out;

    const size_t NODE_F = (size_t)N_NODES * OUT_DIM;   // 6.4M elems

    float*    base     = (float*)d_ws;                          // 25.6 MB
    _Float16* u1h      = (_Float16*)(base + NODE_F);            // 12.8 MB
    float*    m        = (float*)(u1h + NODE_F);                // 25.6 MB
    int*      H        = (int*)(m + NODE_F);                    // H matrix
    int*      Btot     = H + ((size_t)NBUCKETS * NBINBLK + 4);  // NBUCKETS
    int*      node_off = Btot + (NBUCKETS + 4);                 // N_NODES+1
    int*      ebuf     = node_off + (N_NODES + 4);              // 3.2M ints

    // iter 1 collapses: u0 == 0 -> m == 0 -> h == 0 -> u1 = tanh(feature@W_lin)
    gemm_base_tanh<<<1024, 256, 0, stream>>>(feature, W_lin, base, u1h);

    bin_hist  <<<NBINBLK, 256, 0, stream>>>(dst, H);
    scan_local<<<NBUCKETS, NBINBLK, 0, stream>>>(H, Btot);
    scan_tot  <<<1, 1024, 0, stream>>>(Btot);
    add_base  <<<NBUCKETS, NBINBLK, 0, stream>>>(H, Btot);
    bin_scatter<<<NBINBLK, 256, 0, stream>>>(src, dst, H, ebuf);
    bucket_sort<<<NBUCKETS, 256, 0, stream>>>(H, ebuf, node_off);

    int gather_blocks = (int)(((size_t)N_NODES * 64 + 255) / 256);   // 25000
    node_gather<<<gather_blocks, 256, 0, stream>>>(
        node_off, ebuf, (const half8*)u1h, m);

    dense_tanh<<<1024, 256, 0, stream>>>(m, W_d1, W_d2, base, out);
}

// Round 8
// 268.305 us; speedup vs baseline: 7.5426x; 1.1046x over previous
//
#include <hip/hip_runtime.h>
#include <math.h>

#define N_NODES 100000
#define N_EDGES 3200000
#define IN_DIM  128
#define OUT_DIM 64

#define BSHIFT   7
#define BNODES   128                                   // nodes per bucket
#define NBUCKETS ((N_NODES + BNODES - 1) / BNODES)     // 782
#define NBINBLK  1024
#define CHUNK    (N_EDGES / NBINBLK)                   // 3125 (exact)
#define SEGCAP   6144                                  // max edges/bucket

typedef _Float16 half8 __attribute__((ext_vector_type(8)));

__device__ __forceinline__ float rl(float v, int l) {
    return __int_as_float(__builtin_amdgcn_readlane(__float_as_int(v), l));
}

// ---------------------------------------------------------------------------
// Kernel 1: base = feature @ W_lin (fp32) ; u1 = tanh(base) stored as fp16.
// lane = output column; W_lin resident in 128 VGPRs; x via v_readlane.
// ---------------------------------------------------------------------------
__global__ __launch_bounds__(256) void gemm_base_tanh(
    const float* __restrict__ feature,
    const float* __restrict__ Wlin,     // [128][64] row-major
    float* __restrict__ base,
    _Float16* __restrict__ u1h)
{
    int lane = threadIdx.x & 63;
    int wid  = (blockIdx.x * 256 + threadIdx.x) >> 6;
    int nw   = gridDim.x * 4;

    float w[IN_DIM];
#pragma unroll
    for (int k = 0; k < IN_DIM; ++k) w[k] = Wlin[k * OUT_DIM + lane];

    const int NPAIRS = N_NODES / 2;
    for (int p = wid; p < NPAIRS; p += nw) {
        int r0 = 2 * p, r1 = 2 * p + 1;
        float xa0 = feature[(size_t)r0 * IN_DIM + lane];
        float xa1 = feature[(size_t)r0 * IN_DIM + 64 + lane];
        float xb0 = feature[(size_t)r1 * IN_DIM + lane];
        float xb1 = feature[(size_t)r1 * IN_DIM + 64 + lane];

        float acc0 = 0.f, acc1 = 0.f;
#pragma unroll
        for (int k = 0; k < 64; ++k) {
            acc0 = fmaf(rl(xa0, k), w[k], acc0);
            acc1 = fmaf(rl(xb0, k), w[k], acc1);
        }
#pragma unroll
        for (int k = 0; k < 64; ++k) {
            acc0 = fmaf(rl(xa1, k), w[64 + k], acc0);
            acc1 = fmaf(rl(xb1, k), w[64 + k], acc1);
        }

        base[(size_t)r0 * OUT_DIM + lane] = acc0;
        base[(size_t)r1 * OUT_DIM + lane] = acc1;
        u1h[(size_t)r0 * OUT_DIM + lane] = (_Float16)tanhf(acc0);
        u1h[(size_t)r1 * OUT_DIM + lane] = (_Float16)tanhf(acc1);
    }
}

// ---------------------------------------------------------------------------
// Binning phase 1: per-block LDS histogram of dst>>7.  H bucket-major:
// H[k*NBINBLK + b].  1024 blocks -> 4 blocks/CU, latency hidden by TLP.
// ---------------------------------------------------------------------------
__global__ __launch_bounds__(256) void bin_hist(
    const int* __restrict__ dst, int* __restrict__ H)
{
    __shared__ int h[NBUCKETS];
    for (int k = threadIdx.x; k < NBUCKETS; k += 256) h[k] = 0;
    __syncthreads();

    int b = blockIdx.x;
    int beg = b * CHUNK, end = beg + CHUNK;
    for (int i = beg + threadIdx.x; i < end; i += 256)
        atomicAdd(&h[dst[i] >> BSHIFT], 1);
    __syncthreads();

    for (int k = threadIdx.x; k < NBUCKETS; k += 256)
        H[(size_t)k * NBINBLK + b] = h[k];
}

// ---------------------------------------------------------------------------
// Hierarchical scan of H (bucket-major), bit-exact.
// ---------------------------------------------------------------------------
__global__ __launch_bounds__(NBINBLK) void scan_local(
    int* __restrict__ H, int* __restrict__ Btot)
{
    __shared__ int s[NBINBLK];
    int k = blockIdx.x, t = threadIdx.x;
    int v = H[(size_t)k * NBINBLK + t];
    s[t] = v;
    __syncthreads();
#pragma unroll
    for (int off = 1; off < NBINBLK; off <<= 1) {
        int x = (t >= off) ? s[t - off] : 0;
        __syncthreads();
        s[t] += x;
        __syncthreads();
    }
    H[(size_t)k * NBINBLK + t] = s[t] - v;      // exclusive
    if (t == NBINBLK - 1) Btot[k] = s[t];       // inclusive total
}

__global__ __launch_bounds__(1024) void scan_tot(int* __restrict__ Btot)
{
    __shared__ int s[1024];
    int t = threadIdx.x;
    int v = (t < NBUCKETS) ? Btot[t] : 0;
    s[t] = v;
    __syncthreads();
#pragma unroll
    for (int off = 1; off < 1024; off <<= 1) {
        int x = (t >= off) ? s[t - off] : 0;
        __syncthreads();
        s[t] += x;
        __syncthreads();
    }
    if (t < NBUCKETS) Btot[t] = s[t] - v;       // exclusive bucket base
}

__global__ __launch_bounds__(NBINBLK) void add_base(
    int* __restrict__ H, const int* __restrict__ Btot)
{
    int k = blockIdx.x, t = threadIdx.x;
    H[(size_t)k * NBINBLK + t] += Btot[k];
    if (k == 0 && t == 0) H[(size_t)NBUCKETS * NBINBLK] = N_EDGES;
}

// ---------------------------------------------------------------------------
__global__ __launch_bounds__(256) void bin_scatter(
    const int* __restrict__ src,
    const int* __restrict__ dst,
    const int* __restrict__ H,
    int* __restrict__ ebuf)
{
    __shared__ int cur[NBUCKETS];
    int b = blockIdx.x;
    for (int k = threadIdx.x; k < NBUCKETS; k += 256)
        cur[k] = H[(size_t)k * NBINBLK + b];
    __syncthreads();

    int beg = b * CHUNK, end = beg + CHUNK;
    for (int i = beg + threadIdx.x; i < end; i += 256) {
        int d = dst[i];
        int k = d >> BSHIFT;
        int p = atomicAdd(&cur[k], 1);
        // pack: src (17 bits) | dlocal (7 bits) << 17
        ebuf[p] = src[i] | ((d & (BNODES - 1)) << 17);
    }
}

// ---------------------------------------------------------------------------
// Binning phase 2: per-bucket in-LDS counting sort by node.  Rewrites ebuf
// in place (src only, node-sorted) and emits exact per-node CSR offsets.
// ---------------------------------------------------------------------------
__global__ __launch_bounds__(256) void bucket_sort(
    const int* __restrict__ H,
    int* __restrict__ ebuf,
    int* __restrict__ node_off)
{
    __shared__ int seg[SEGCAP];
    __shared__ int cnt[BNODES];
    __shared__ int off[BNODES];
    int k = blockIdx.x;
    int beg = H[(size_t)k * NBINBLK];
    int end = H[(size_t)(k + 1) * NBINBLK];
    int n = end - beg;

    for (int j = threadIdx.x; j < BNODES; j += 256) cnt[j] = 0;
    __syncthreads();

    for (int i = threadIdx.x; i < n; i += 256) {
        int v = ebuf[beg + i];
        seg[i] = v;
        atomicAdd(&cnt[v >> 17], 1);
    }
    __syncthreads();

    if (threadIdx.x == 0) {
        int node0 = k * BNODES;
        int nvalid = N_NODES - node0; if (nvalid > BNODES) nvalid = BNODES;
        int excl = 0;
        for (int j = 0; j < nvalid; ++j) {
            off[j] = excl;
            node_off[node0 + j] = beg + excl;
            excl += cnt[j];
        }
        if (k == NBUCKETS - 1) node_off[N_NODES] = end;
    }
    __syncthreads();

    for (int i = threadIdx.x; i < n; i += 256) {
        int v = seg[i];
        int p = atomicAdd(&off[v >> 17], 1);
        ebuf[beg + p] = v & 0x1FFFF;
    }
}

// ---------------------------------------------------------------------------
// Gather: one wave per node over fp16 u1 rows (128 B each).
// lane (q,c): q=lane>>3 = edge slot (8 edges/wave-step), c=lane&7 = 16 B
// half8 column chunk.  4-deep unroll -> 32 edges in flight per wave.
// fp32 register accumulate, shfl-xor(8,16,32) reduce, 256 B coalesced store.
// ---------------------------------------------------------------------------
__global__ __launch_bounds__(256) void node_gather(
    const int* __restrict__ node_off,
    const int* __restrict__ csr,
    const half8* __restrict__ u1v,      // [N_NODES][8]
    float* __restrict__ m)
{
    int wid = (blockIdx.x * 256 + threadIdx.x) >> 6;
    if (wid >= N_NODES) return;
    int lane = threadIdx.x & 63;
    int q = lane >> 3, c = lane & 7;

    int beg = node_off[wid];
    int end = node_off[wid + 1];

    float acc[8];
#pragma unroll
    for (int i = 0; i < 8; ++i) acc[i] = 0.f;

    int e = beg + q;
    for (; e + 24 < end; e += 32) {
        int s0 = csr[e];
        int s1 = csr[e + 8];
        int s2 = csr[e + 16];
        int s3 = csr[e + 24];
        half8 a = u1v[(size_t)s0 * 8 + c];
        half8 b = u1v[(size_t)s1 * 8 + c];
        half8 g = u1v[(size_t)s2 * 8 + c];
        half8 d = u1v[(size_t)s3 * 8 + c];
#pragma unroll
        for (int i = 0; i < 8; ++i)
            acc[i] += ((float)a[i] + (float)b[i]) + ((float)g[i] + (float)d[i]);
    }
    for (; e < end; e += 8) {
        half8 a = u1v[(size_t)csr[e] * 8 + c];
#pragma unroll
        for (int i = 0; i < 8; ++i) acc[i] += (float)a[i];
    }

    // reduce across the 8 q-groups (lane bits 3,4,5)
#pragma unroll
    for (int i = 0; i < 8; ++i) {
        acc[i] += __shfl_xor(acc[i], 8);
        acc[i] += __shfl_xor(acc[i], 16);
        acc[i] += __shfl_xor(acc[i], 32);
    }

    if (q == 0) {
        float4* mr = reinterpret_cast<float4*>(m + (size_t)wid * OUT_DIM + c * 8);
        mr[0] = make_float4(acc[0], acc[1], acc[2], acc[3]);
        mr[1] = make_float4(acc[4], acc[5], acc[6], acc[7]);
    }
}

// ---------------------------------------------------------------------------
// Kernel 3: out = tanh(base + relu(m @ W_d1) @ W_d2)
// lane = column; W_d1/W_d2 resident in 64+64 VGPRs; x via readlane.
// ---------------------------------------------------------------------------
__global__ __launch_bounds__(256) void dense_tanh(
    const float* __restrict__ m,
    const float* __restrict__ W1,       // [64][64]
    const float* __restrict__ W2,       // [64][64]
    const float* __restrict__ base,
    float* __restrict__ out)
{
    int lane = threadIdx.x & 63;
    int wid  = (blockIdx.x * 256 + threadIdx.x) >> 6;
    int nw   = gridDim.x * 4;

    float w1[64], w2[64];
#pragma unroll
    for (int k = 0; k < 64; ++k) w1[k] = W1[k * 64 + lane];
#pragma unroll
    for (int k = 0; k < 64; ++k) w2[k] = W2[k * 64 + lane];

    const int NPAIRS = N_NODES / 2;
    for (int p = wid; p < NPAIRS; p += nw) {
        int r0 = 2 * p, r1 = 2 * p + 1;
        float x0 = m[(size_t)r0 * 64 + lane];
        float x1 = m[(size_t)r1 * 64 + lane];

        float a0 = 0.f, a1 = 0.f;
#pragma unroll
        for (int k = 0; k < 64; ++k) {
            a0 = fmaf(rl(x0, k), w1[k], a0);
            a1 = fmaf(rl(x1, k), w1[k], a1);
        }
        float t0 = fmaxf(a0, 0.f);
        float t1 = fmaxf(a1, 0.f);

        float h0 = 0.f, h1 = 0.f;
#pragma unroll
        for (int k = 0; k < 64; ++k) {
            h0 = fmaf(rl(t0, k), w2[k], h0);
            h1 = fmaf(rl(t1, k), w2[k], h1);
        }

        float b0 = base[(size_t)r0 * 64 + lane];
        float b1 = base[(size_t)r1 * 64 + lane];
        out[(size_t)r0 * 64 + lane] = tanhf(b0 + h0);
        out[(size_t)r1 * 64 + lane] = tanhf(b1 + h1);
    }
}

// ---------------------------------------------------------------------------
extern "C" void kernel_launch(void* const* d_in, const int* in_sizes, int n_in,
                              void* d_out, int out_size, void* d_ws, size_t ws_size,
                              hipStream_t stream)
{
    const float* feature = (const float*)d_in[0];
    const int*   src     = (const int*)d_in[1];
    const int*   dst     = (const int*)d_in[2];
    const float* W_lin   = (const float*)d_in[3];
    const float* W_d1    = (const float*)d_in[4];
    const float* W_d2    = (const float*)d_in[5];
    float* out = (float*)d_out;

    const size_t NODE_F = (size_t)N_NODES * OUT_DIM;   // 6.4M elems

    float*    base     = (float*)d_ws;                          // 25.6 MB
    _Float16* u1h      = (_Float16*)(base + NODE_F);            // 12.8 MB
    float*    m        = (float*)(u1h + NODE_F);                // 25.6 MB
    int*      H        = (int*)(m + NODE_F);                    // 3.2 MB
    int*      Btot     = H + ((size_t)NBUCKETS * NBINBLK + 4);  // NBUCKETS
    int*      node_off = Btot + (NBUCKETS + 4);                 // N_NODES+1
    int*      ebuf     = node_off + (N_NODES + 4);              // 3.2M ints

    // iter 1 collapses: u0 == 0 -> m == 0 -> h == 0 -> u1 = tanh(feature@W_lin)
    gemm_base_tanh<<<1024, 256, 0, stream>>>(feature, W_lin, base, u1h);

    bin_hist  <<<NBINBLK, 256, 0, stream>>>(dst, H);
    scan_local<<<NBUCKETS, NBINBLK, 0, stream>>>(H, Btot);
    scan_tot  <<<1, 1024, 0, stream>>>(Btot);
    add_base  <<<NBUCKETS, NBINBLK, 0, stream>>>(H, Btot);
    bin_scatter<<<NBINBLK, 256, 0, stream>>>(src, dst, H, ebuf);
    bucket_sort<<<NBUCKETS, 256, 0, stream>>>(H, ebuf, node_off);

    int gather_blocks = (int)(((size_t)N_NODES * 64 + 255) / 256);   // 25000
    node_gather<<<gather_blocks, 256, 0, stream>>>(
        node_off, ebuf, (const half8*)u1h, m);

    dense_tanh<<<1024, 256, 0, stream>>>(m, W_d1, W_d2, base, out);
}

// Round 9
// 227.695 us; speedup vs baseline: 8.8878x; 1.1783x over previous
//
#include <hip/hip_runtime.h>
#include <math.h>

#define N_NODES 100000
#define N_EDGES 3200000
#define IN_DIM  128
#define OUT_DIM 64

#define BSHIFT   7
#define BNODES   128                                   // nodes per bucket
#define NBUCKETS ((N_NODES + BNODES - 1) / BNODES)     // 782
#define NBINBLK  1024
#define CHUNK    (N_EDGES / NBINBLK)                   // 3125 (exact)
#define SEGCAP   6144                                  // max edges/bucket
#define MTILES   (N_NODES / 16)                        // 6250 (exact)

typedef _Float16 half8 __attribute__((ext_vector_type(8)));
typedef float    f32x4 __attribute__((ext_vector_type(4)));

__device__ __forceinline__ float rl(float v, int l) {
    return __int_as_float(__builtin_amdgcn_readlane(__float_as_int(v), l));
}

// ---------------------------------------------------------------------------
// Kernel 1 (MFMA): base = feature @ W_lin ; u1 = tanh(base) as fp16.
// One wave per 16-row m-tile.  mfma_f32_16x16x32_f16:
//   A frag: lane l holds feature[tile*16 + (l&15)][kb*8 .. kb*8+7], kb=l>>4
//   B frag: lane l holds W[kb*8+j][n*16 + (l&15)]
//   C/D:    col = lane&15, row = (lane>>4)*4 + reg   (m89, dtype-indep)
// fp16 inputs, fp32 accumulate.  16 MFMAs per tile (4 ksteps x 4 col-frags).
// ---------------------------------------------------------------------------
__global__ __launch_bounds__(256) void gemm_base_tanh(
    const float* __restrict__ feature,
    const float* __restrict__ Wlin,     // [128][64] row-major fp32
    float* __restrict__ base,
    _Float16* __restrict__ u1h)
{
    int lane = threadIdx.x & 63;
    int wid  = (blockIdx.x * 256 + threadIdx.x) >> 6;
    if (wid >= MTILES) return;

    int mrow = lane & 15;       // A row / B col / C col
    int kb   = lane >> 4;       // k-block 0..3
    int k0   = kb * 8;

    // B fragments (whole W, fp16): b[s][n] = W[s*32 + k0 + j][n*16 + mrow]
    half8 b[4][4];
#pragma unroll
    for (int s = 0; s < 4; ++s)
#pragma unroll
        for (int n = 0; n < 4; ++n)
#pragma unroll
            for (int j = 0; j < 8; ++j)
                b[s][n][j] = (_Float16)Wlin[(s * 32 + k0 + j) * OUT_DIM + n * 16 + mrow];

    // A fragments: a[s] = feature[row][s*32 + k0 .. +7]
    int row = wid * 16 + mrow;
    const float4* fr = reinterpret_cast<const float4*>(feature + (size_t)row * IN_DIM);
    half8 a[4];
#pragma unroll
    for (int s = 0; s < 4; ++s) {
        float4 lo = fr[(s * 32 + k0) >> 2];
        float4 hi = fr[((s * 32 + k0) >> 2) + 1];
        a[s][0] = (_Float16)lo.x; a[s][1] = (_Float16)lo.y;
        a[s][2] = (_Float16)lo.z; a[s][3] = (_Float16)lo.w;
        a[s][4] = (_Float16)hi.x; a[s][5] = (_Float16)hi.y;
        a[s][6] = (_Float16)hi.z; a[s][7] = (_Float16)hi.w;
    }

    f32x4 acc[4];
#pragma unroll
    for (int n = 0; n < 4; ++n) acc[n] = (f32x4)0.f;

#pragma unroll
    for (int s = 0; s < 4; ++s)
#pragma unroll
        for (int n = 0; n < 4; ++n)
            acc[n] = __builtin_amdgcn_mfma_f32_16x16x32_f16(a[s], b[s][n], acc[n], 0, 0, 0);

    // epilogue: base fp32 + u1 = tanh(base) fp16
#pragma unroll
    for (int n = 0; n < 4; ++n)
#pragma unroll
        for (int j = 0; j < 4; ++j) {
            int r = wid * 16 + kb * 4 + j;
            int c = n * 16 + mrow;
            float v = acc[n][j];
            base[(size_t)r * OUT_DIM + c] = v;
            u1h[(size_t)r * OUT_DIM + c] = (_Float16)tanhf(v);
        }
}

// ---------------------------------------------------------------------------
// Binning phase 1: per-block LDS histogram of dst>>7.  H bucket-major:
// H[k*NBINBLK + b].  1024 blocks -> 4 blocks/CU, latency hidden by TLP.
// ---------------------------------------------------------------------------
__global__ __launch_bounds__(256) void bin_hist(
    const int* __restrict__ dst, int* __restrict__ H)
{
    __shared__ int h[NBUCKETS];
    for (int k = threadIdx.x; k < NBUCKETS; k += 256) h[k] = 0;
    __syncthreads();

    int b = blockIdx.x;
    int beg = b * CHUNK, end = beg + CHUNK;
    for (int i = beg + threadIdx.x; i < end; i += 256)
        atomicAdd(&h[dst[i] >> BSHIFT], 1);
    __syncthreads();

    for (int k = threadIdx.x; k < NBUCKETS; k += 256)
        H[(size_t)k * NBINBLK + b] = h[k];
}

// ---------------------------------------------------------------------------
// Hierarchical scan of H (bucket-major), bit-exact.
// ---------------------------------------------------------------------------
__global__ __launch_bounds__(NBINBLK) void scan_local(
    int* __restrict__ H, int* __restrict__ Btot)
{
    __shared__ int s[NBINBLK];
    int k = blockIdx.x, t = threadIdx.x;
    int v = H[(size_t)k * NBINBLK + t];
    s[t] = v;
    __syncthreads();
#pragma unroll
    for (int off = 1; off < NBINBLK; off <<= 1) {
        int x = (t >= off) ? s[t - off] : 0;
        __syncthreads();
        s[t] += x;
        __syncthreads();
    }
    H[(size_t)k * NBINBLK + t] = s[t] - v;      // exclusive
    if (t == NBINBLK - 1) Btot[k] = s[t];       // inclusive total
}

__global__ __launch_bounds__(1024) void scan_tot(int* __restrict__ Btot)
{
    __shared__ int s[1024];
    int t = threadIdx.x;
    int v = (t < NBUCKETS) ? Btot[t] : 0;
    s[t] = v;
    __syncthreads();
#pragma unroll
    for (int off = 1; off < 1024; off <<= 1) {
        int x = (t >= off) ? s[t - off] : 0;
        __syncthreads();
        s[t] += x;
        __syncthreads();
    }
    if (t < NBUCKETS) Btot[t] = s[t] - v;       // exclusive bucket base
}

__global__ __launch_bounds__(NBINBLK) void add_base(
    int* __restrict__ H, const int* __restrict__ Btot)
{
    int k = blockIdx.x, t = threadIdx.x;
    H[(size_t)k * NBINBLK + t] += Btot[k];
    if (k == 0 && t == 0) H[(size_t)NBUCKETS * NBINBLK] = N_EDGES;
}

// ---------------------------------------------------------------------------
__global__ __launch_bounds__(256) void bin_scatter(
    const int* __restrict__ src,
    const int* __restrict__ dst,
    const int* __restrict__ H,
    int* __restrict__ ebuf)
{
    __shared__ int cur[NBUCKETS];
    int b = blockIdx.x;
    for (int k = threadIdx.x; k < NBUCKETS; k += 256)
        cur[k] = H[(size_t)k * NBINBLK + b];
    __syncthreads();

    int beg = b * CHUNK, end = beg + CHUNK;
    for (int i = beg + threadIdx.x; i < end; i += 256) {
        int d = dst[i];
        int k = d >> BSHIFT;
        int p = atomicAdd(&cur[k], 1);
        // pack: src (17 bits) | dlocal (7 bits) << 17
        ebuf[p] = src[i] | ((d & (BNODES - 1)) << 17);
    }
}

// ---------------------------------------------------------------------------
// Binning phase 2: per-bucket in-LDS counting sort by node.  Rewrites ebuf
// in place (src only, node-sorted) and emits exact per-node CSR offsets.
// ---------------------------------------------------------------------------
__global__ __launch_bounds__(256) void bucket_sort(
    const int* __restrict__ H,
    int* __restrict__ ebuf,
    int* __restrict__ node_off)
{
    __shared__ int seg[SEGCAP];
    __shared__ int cnt[BNODES];
    __shared__ int off[BNODES];
    int k = blockIdx.x;
    int beg = H[(size_t)k * NBINBLK];
    int end = H[(size_t)(k + 1) * NBINBLK];
    int n = end - beg;

    for (int j = threadIdx.x; j < BNODES; j += 256) cnt[j] = 0;
    __syncthreads();

    for (int i = threadIdx.x; i < n; i += 256) {
        int v = ebuf[beg + i];
        seg[i] = v;
        atomicAdd(&cnt[v >> 17], 1);
    }
    __syncthreads();

    if (threadIdx.x == 0) {
        int node0 = k * BNODES;
        int nvalid = N_NODES - node0; if (nvalid > BNODES) nvalid = BNODES;
        int excl = 0;
        for (int j = 0; j < nvalid; ++j) {
            off[j] = excl;
            node_off[node0 + j] = beg + excl;
            excl += cnt[j];
        }
        if (k == NBUCKETS - 1) node_off[N_NODES] = end;
    }
    __syncthreads();

    for (int i = threadIdx.x; i < n; i += 256) {
        int v = seg[i];
        int p = atomicAdd(&off[v >> 17], 1);
        ebuf[beg + p] = v & 0x1FFFF;
    }
}

// ---------------------------------------------------------------------------
// Gather: one wave per node over fp16 u1 rows (128 B each).
// lane (q,c): q=lane>>3 = edge slot (8 edges/wave-step), c=lane&7 = 16 B
// half8 column chunk.  4-deep unroll -> 32 edges in flight per wave.
// fp32 register accumulate, shfl-xor(8,16,32) reduce, 256 B coalesced store.
// ---------------------------------------------------------------------------
__global__ __launch_bounds__(256) void node_gather(
    const int* __restrict__ node_off,
    const int* __restrict__ csr,
    const half8* __restrict__ u1v,      // [N_NODES][8]
    float* __restrict__ m)
{
    int wid = (blockIdx.x * 256 + threadIdx.x) >> 6;
    if (wid >= N_NODES) return;
    int lane = threadIdx.x & 63;
    int q = lane >> 3, c = lane & 7;

    int beg = node_off[wid];
    int end = node_off[wid + 1];

    float acc[8];
#pragma unroll
    for (int i = 0; i < 8; ++i) acc[i] = 0.f;

    int e = beg + q;
    for (; e + 24 < end; e += 32) {
        int s0 = csr[e];
        int s1 = csr[e + 8];
        int s2 = csr[e + 16];
        int s3 = csr[e + 24];
        half8 a = u1v[(size_t)s0 * 8 + c];
        half8 b = u1v[(size_t)s1 * 8 + c];
        half8 g = u1v[(size_t)s2 * 8 + c];
        half8 d = u1v[(size_t)s3 * 8 + c];
#pragma unroll
        for (int i = 0; i < 8; ++i)
            acc[i] += ((float)a[i] + (float)b[i]) + ((float)g[i] + (float)d[i]);
    }
    for (; e < end; e += 8) {
        half8 a = u1v[(size_t)csr[e] * 8 + c];
#pragma unroll
        for (int i = 0; i < 8; ++i) acc[i] += (float)a[i];
    }

    // reduce across the 8 q-groups (lane bits 3,4,5)
#pragma unroll
    for (int i = 0; i < 8; ++i) {
        acc[i] += __shfl_xor(acc[i], 8);
        acc[i] += __shfl_xor(acc[i], 16);
        acc[i] += __shfl_xor(acc[i], 32);
    }

    if (q == 0) {
        float4* mr = reinterpret_cast<float4*>(m + (size_t)wid * OUT_DIM + c * 8);
        mr[0] = make_float4(acc[0], acc[1], acc[2], acc[3]);
        mr[1] = make_float4(acc[4], acc[5], acc[6], acc[7]);
    }
}

// ---------------------------------------------------------------------------
// Kernel 3: out = tanh(base + relu(m @ W_d1) @ W_d2)
// lane = column; W_d1/W_d2 resident in 64+64 VGPRs; x via readlane.
// ---------------------------------------------------------------------------
__global__ __launch_bounds__(256) void dense_tanh(
    const float* __restrict__ m,
    const float* __restrict__ W1,       // [64][64]
    const float* __restrict__ W2,       // [64][64]
    const float* __restrict__ base,
    float* __restrict__ out)
{
    int lane = threadIdx.x & 63;
    int wid  = (blockIdx.x * 256 + threadIdx.x) >> 6;
    int nw   = gridDim.x * 4;

    float w1[64], w2[64];
#pragma unroll
    for (int k = 0; k < 64; ++k) w1[k] = W1[k * 64 + lane];
#pragma unroll
    for (int k = 0; k < 64; ++k) w2[k] = W2[k * 64 + lane];

    const int NPAIRS = N_NODES / 2;
    for (int p = wid; p < NPAIRS; p += nw) {
        int r0 = 2 * p, r1 = 2 * p + 1;
        float x0 = m[(size_t)r0 * 64 + lane];
        float x1 = m[(size_t)r1 * 64 + lane];

        float a0 = 0.f, a1 = 0.f;
#pragma unroll
        for (int k = 0; k < 64; ++k) {
            a0 = fmaf(rl(x0, k), w1[k], a0);
            a1 = fmaf(rl(x1, k), w1[k], a1);
        }
        float t0 = fmaxf(a0, 0.f);
        float t1 = fmaxf(a1, 0.f);

        float h0 = 0.f, h1 = 0.f;
#pragma unroll
        for (int k = 0; k < 64; ++k) {
            h0 = fmaf(rl(t0, k), w2[k], h0);
            h1 = fmaf(rl(t1, k), w2[k], h1);
        }

        float b0 = base[(size_t)r0 * 64 + lane];
        float b1 = base[(size_t)r1 * 64 + lane];
        out[(size_t)r0 * 64 + lane] = tanhf(b0 + h0);
        out[(size_t)r1 * 64 + lane] = tanhf(b1 + h1);
    }
}

// ---------------------------------------------------------------------------
extern "C" void kernel_launch(void* const* d_in, const int* in_sizes, int n_in,
                              void* d_out, int out_size, void* d_ws, size_t ws_size,
                              hipStream_t stream)
{
    const float* feature = (const float*)d_in[0];
    const int*   src     = (const int*)d_in[1];
    const int*   dst     = (const int*)d_in[2];
    const float* W_lin   = (const float*)d_in[3];
    const float* W_d1    = (const float*)d_in[4];
    const float* W_d2    = (const float*)d_in[5];
    float* out = (float*)d_out;

    const size_t NODE_F = (size_t)N_NODES * OUT_DIM;   // 6.4M elems

    float*    base     = (float*)d_ws;                          // 25.6 MB
    _Float16* u1h      = (_Float16*)(base + NODE_F);            // 12.8 MB
    float*    m        = (float*)(u1h + NODE_F);                // 25.6 MB
    int*      H        = (int*)(m + NODE_F);                    // 3.2 MB
    int*      Btot     = H + ((size_t)NBUCKETS * NBINBLK + 4);  // NBUCKETS
    int*      node_off = Btot + (NBUCKETS + 4);                 // N_NODES+1
    int*      ebuf     = node_off + (N_NODES + 4);              // 3.2M ints

    // iter 1 collapses: u0 == 0 -> m == 0 -> h == 0 -> u1 = tanh(feature@W_lin)
    int gemm_blocks = (MTILES + 3) / 4;                // 4 waves/block
    gemm_base_tanh<<<gemm_blocks, 256, 0, stream>>>(feature, W_lin, base, u1h);

    bin_hist  <<<NBINBLK, 256, 0, stream>>>(dst, H);
    scan_local<<<NBUCKETS, NBINBLK, 0, stream>>>(H, Btot);
    scan_tot  <<<1, 1024, 0, stream>>>(Btot);
    add_base  <<<NBUCKETS, NBINBLK, 0, stream>>>(H, Btot);
    bin_scatter<<<NBINBLK, 256, 0, stream>>>(src, dst, H, ebuf);
    bucket_sort<<<NBUCKETS, 256, 0, stream>>>(H, ebuf, node_off);

    int gather_blocks = (int)(((size_t)N_NODES * 64 + 255) / 256);   // 25000
    node_gather<<<gather_blocks, 256, 0, stream>>>(
        node_off, ebuf, (const half8*)u1h, m);

    dense_tanh<<<1024, 256, 0, stream>>>(m, W_d1, W_d2, base, out);
}